// Round 7
// baseline (392.053 us; speedup 1.0000x reference)
//
#include <hip/hip_runtime.h>
#include <stdint.h>

#define N_ALL   16384
#define NPOINT  4096
#define KNN_K   32
#define BATCH   2
#define P_TOT   (BATCH*NPOINT*KNN_K)   /* 262144 */
#define P_TOTF  262144.0f
#define EPSV    1e-5f

typedef __attribute__((ext_vector_type(8))) short bf16x8;
typedef __attribute__((ext_vector_type(4))) float f32x4;

// ---- all scratch in module-static device memory; d_ws untouched ----
__device__ unsigned short g_knn[P_TOT];                                   // 512 KB
__device__ __attribute__((aligned(16))) float g_pxyzn[BATCH*N_ALL*4];     // 512 KB (x,y,z,|x|^2)
__device__ __attribute__((aligned(16))) short g_ptb[BATCH*N_ALL*64];      // 4 MB  [b,n][64c] bf16
__device__ __attribute__((aligned(16))) short g_x0b[(size_t)P_TOT*64];    // 32 MB [p][64] bf16
__device__ __attribute__((aligned(16))) short g_x1b[(size_t)P_TOT*64];    // 32 MB
__device__ __attribute__((aligned(16))) short g_x2b[(size_t)P_TOT*128];   // 64 MB
__device__ __attribute__((aligned(16))) short g_Wb0[4*3*64*8];            // swizzled A-frags
__device__ __attribute__((aligned(16))) short g_Wb1[4*2*64*8];
__device__ __attribute__((aligned(16))) short g_Wb2[8*2*64*8];
__device__ float g_part0[128], g_part1[128], g_part2[256];

__device__ __forceinline__ float b2f(short s) {
  union { unsigned u; float f; } v; v.u = ((unsigned)(unsigned short)s) << 16; return v.f;
}
__device__ __forceinline__ short f2b(float f) {
  union { float f; unsigned u; } v; v.f = f;
  unsigned u = v.u;
  u += 0x7FFFu + ((u >> 16) & 1u);
  return (short)(u >> 16);
}
__device__ __forceinline__ unsigned long long bperm64(unsigned long long v, int byteaddr) {
  int lo = __builtin_amdgcn_ds_bpermute(byteaddr, (int)(unsigned)(v & 0xFFFFFFFFULL));
  int hi = __builtin_amdgcn_ds_bpermute(byteaddr, (int)(unsigned)(v >> 32));
  return (((unsigned long long)(unsigned)hi) << 32) | (unsigned)lo;
}
__device__ __forceinline__ unsigned long long u64min(unsigned long long a, unsigned long long b) {
  return a < b ? a : b;
}
// bitonic compare-exchange step: keep min (mx=0) or max (mx=1) of (v, pv)
__device__ __forceinline__ unsigned long long selstage(unsigned long long v,
                                                       unsigned long long pv, bool mx) {
  bool lt = v < pv;
  return (lt != mx) ? v : pv;
}

// sort 32 buffered candidates (vB, one per lane within a 32-lane half) ascending,
// merge lowest-32 of (vL ∪ vB) back into vL (sorted), refresh worst_hi/wd.
__device__ __forceinline__ void knn_merge32(unsigned long long& vL,
                                            unsigned long long& worst,
                                            unsigned& worst_hi, float& wd,
                                            unsigned long long vB, int hl,
                                            int aX1, int aX2, int aX4, int aX8,
                                            int aX16, int aRev, int aW) {
  vB = selstage(vB, bperm64(vB, aX1),  ((hl & 1) != 0) != ((hl & 2) != 0));
  vB = selstage(vB, bperm64(vB, aX2),  ((hl & 2) != 0) != ((hl & 4) != 0));
  vB = selstage(vB, bperm64(vB, aX1),  ((hl & 1) != 0) != ((hl & 4) != 0));
  vB = selstage(vB, bperm64(vB, aX4),  ((hl & 4) != 0) != ((hl & 8) != 0));
  vB = selstage(vB, bperm64(vB, aX2),  ((hl & 2) != 0) != ((hl & 8) != 0));
  vB = selstage(vB, bperm64(vB, aX1),  ((hl & 1) != 0) != ((hl & 8) != 0));
  vB = selstage(vB, bperm64(vB, aX8),  ((hl & 8) != 0) != ((hl & 16) != 0));
  vB = selstage(vB, bperm64(vB, aX4),  ((hl & 4) != 0) != ((hl & 16) != 0));
  vB = selstage(vB, bperm64(vB, aX2),  ((hl & 2) != 0) != ((hl & 16) != 0));
  vB = selstage(vB, bperm64(vB, aX1),  ((hl & 1) != 0) != ((hl & 16) != 0));
  vB = selstage(vB, bperm64(vB, aX16), (hl & 16) != 0);
  vB = selstage(vB, bperm64(vB, aX8),  (hl & 8) != 0);
  vB = selstage(vB, bperm64(vB, aX4),  (hl & 4) != 0);
  vB = selstage(vB, bperm64(vB, aX2),  (hl & 2) != 0);
  vB = selstage(vB, bperm64(vB, aX1),  (hl & 1) != 0);
  // vL asc, vB asc: pair lane i with reversed buffer -> lowest 32 (bitonic), then cleanup
  vL = u64min(vL, bperm64(vB, aRev));
  vL = selstage(vL, bperm64(vL, aX16), (hl & 16) != 0);
  vL = selstage(vL, bperm64(vL, aX8),  (hl & 8) != 0);
  vL = selstage(vL, bperm64(vL, aX4),  (hl & 4) != 0);
  vL = selstage(vL, bperm64(vL, aX2),  (hl & 2) != 0);
  vL = selstage(vL, bperm64(vL, aX1),  (hl & 1) != 0);
  worst = bperm64(vL, aW);
  worst_hi = (unsigned)(worst >> 32);
  unsigned wh = worst_hi;
  unsigned ub = (wh & 0x80000000u) ? (wh ^ 0x80000000u) : ~wh;
  wd = (wh == 0xFFFFFFFFu) ? __builtin_inff() : __uint_as_float(ub);
}

// ---------------- setup: tpose (blk<512) | copy+pack (512..639) | wprep (640) ----------------
__global__ __launch_bounds__(256) void k_setup(const float* __restrict__ xyz,
                                               const float* __restrict__ points,
                                               const float* __restrict__ W0,
                                               const float* __restrict__ W1,
                                               const float* __restrict__ W2,
                                               float* __restrict__ out) {
#pragma clang fp contract(off)
  __shared__ float tile[64][65];
  int blk = blockIdx.x;
  int t = threadIdx.x;
  if (blk < 512) {
    int b  = blk >> 8;
    int n0 = (blk & 255) << 6;
#pragma unroll
    for (int r = 0; r < 16; r++) {
      int lin = r * 256 + t;
      int c = lin >> 6, nn = lin & 63;
      tile[c][nn] = points[((size_t)(b * 64 + c)) * N_ALL + n0 + nn];
    }
    __syncthreads();
#pragma unroll
    for (int r = 0; r < 16; r++) {
      int lin = r * 256 + t;
      int nn = lin >> 6, c = lin & 63;
      g_ptb[((size_t)(b * N_ALL + n0 + nn)) * 64 + c] = f2b(tile[c][nn]);
    }
  } else if (blk < 640) {
    int i = (blk - 512) * 256 + t;   // < 32768
    if (i < 24576) {
      int s = i & 4095;
      int c = (i >> 12) % 3;
      int b = i / 12288;
      out[i] = xyz[(b * 3 + c) * N_ALL + s];
    }
    int b = i >> 14, n = i & 16383;
    const float* xb = xyz + b * 3 * N_ALL;
    float x = xb[n], y = xb[N_ALL + n], z = xb[2 * N_ALL + n];
    float4 p; p.x = x; p.y = y; p.z = z; p.w = x * x + y * y + z * z;
    ((float4*)g_pxyzn)[i] = p;
  } else {
    for (int i = t; i < 4 * 3 * 64 * 8; i += 256) {
      int j = i & 7, lane = (i >> 3) & 63, rest = i >> 9;
      int kt = rest % 3, mt = rest / 3;
      int m = 16 * mt + (lane & 15);
      int k = 32 * kt + (lane >> 4) * 8 + j;
      float v = 0.f;
      if (k < 64) v = W0[m * 67 + 3 + k];
      else if (k < 67) v = W0[m * 67 + (k - 64)];
      g_Wb0[i] = f2b(v);
    }
    for (int i = t; i < 4 * 2 * 64 * 8; i += 256) {
      int j = i & 7, lane = (i >> 3) & 63;
      int kt = (i >> 9) & 1, mt = i >> 10;
      int m = 16 * mt + (lane & 15);
      int k = 32 * kt + (lane >> 4) * 8 + j;
      g_Wb1[i] = f2b(W1[m * 64 + k]);
    }
    for (int i = t; i < 8 * 2 * 64 * 8; i += 256) {
      int j = i & 7, lane = (i >> 3) & 63;
      int kt = (i >> 9) & 1, mt = i >> 10;
      int m = 16 * mt + (lane & 15);
      int k = 32 * kt + (lane >> 4) * 8 + j;
      g_Wb2[i] = f2b(W2[m * 64 + k]);
    }
    if (t < 128) { g_part0[t] = 0.f; g_part1[t] = 0.f; }
    g_part2[t] = 0.f;
  }
}

// ---------------- KNN: split-N 2-way, 2 queries/wave, float gate + survivor-only keys ----------------
__global__ __launch_bounds__(256, 8) void k_knn() {
#pragma clang fp contract(off)
  __shared__ unsigned long long buf[4][2][64];
  int wv = threadIdx.x >> 6;
  int lane = threadIdx.x & 63;
  int half = lane >> 5;            // 0: lanes 0..31 (query A), 1: lanes 32..63 (query B)
  int hl = lane & 31;
  int lanebase = lane & 32;
  unsigned long long* bufh = buf[wv][half];

  int qpair = wv >> 1;             // waves {0,1} share queries, {2,3} share queries
  int range = wv & 1;              // 0: points [0,8192), 1: [8192,16384)
  int q = blockIdx.x * 4 + qpair * 2 + half;   // 0..8191
  int b = q >> 12, s = q & 4095;
  const float4* pb = (const float4*)g_pxyzn + (b << 14);
  float4 qp = pb[s];
  float qx = qp.x, qy = qp.y, qz = qp.z, qn = qp.w;

  // hoisted cross-lane byte addresses (stay within own 32-lane half)
  int aX1  = (lanebase | (hl ^ 1))  << 2;
  int aX2  = (lanebase | (hl ^ 2))  << 2;
  int aX4  = (lanebase | (hl ^ 4))  << 2;
  int aX8  = (lanebase | (hl ^ 8))  << 2;
  int aX16 = (lanebase | (hl ^ 16)) << 2;
  int aRev = (lanebase | (31 - hl)) << 2;
  int aW   = (lanebase | 31)        << 2;

  unsigned long long vL = ~0ULL;      // per-half sorted top-32 (ascending by lane)
  unsigned long long worst = ~0ULL;   // per-lane copy of own half's vL[31]
  unsigned worst_hi = 0xFFFFFFFFu;
  float wd = __builtin_inff();        // worst distance as float (conservative gate)
  int F = 0;                          // buffered-candidate count (uniform within half)

  int base = range << 13;
  for (int n0 = base; n0 < base + 8192; n0 += 128) {
    float4 p0 = pb[n0 + hl];
    float4 p1 = pb[n0 + 32 + hl];
    float4 p2 = pb[n0 + 64 + hl];
    float4 p3 = pb[n0 + 96 + hl];
    float d[4];
    {
      float dt0 = (qx * p0.x + qy * p0.y) + qz * p0.z;   // contract off: exact ref order
      float dt1 = (qx * p1.x + qy * p1.y) + qz * p1.z;
      float dt2 = (qx * p2.x + qy * p2.y) + qz * p2.z;
      float dt3 = (qx * p3.x + qy * p3.y) + qz * p3.z;
      d[0] = __builtin_fmaf(-2.0f, dt0, qn + p0.w);      // == (qn+pn) - 2*dt exactly
      d[1] = __builtin_fmaf(-2.0f, dt1, qn + p1.w);
      d[2] = __builtin_fmaf(-2.0f, dt2, qn + p2.w);
      d[3] = __builtin_fmaf(-2.0f, dt3, qn + p3.w);
    }
    float md = fminf(fminf(d[0], d[1]), fminf(d[2], d[3]));
    if (__ballot(md <= wd)) {
#pragma unroll
      for (int t = 0; t < 4; t++) {
        bool sv = d[t] <= wd;           // float gate: conservative superset of exact u64 test
        unsigned long long bl = __ballot(sv);
        unsigned mb = half ? (unsigned)(bl >> 32) : (unsigned)bl;
        if (sv) {                       // survivors only: build exact u64 key (masked, no branch)
          unsigned u = __float_as_uint(d[t]);
          u ^= ((unsigned)(((int)u) >> 31)) | 0x80000000u;   // order-preserving map
          unsigned long long c = (((unsigned long long)u) << 32)
                               | (unsigned)(n0 + 32 * t + hl);
          bufh[F + __popc(mb & ((1u << hl) - 1u))] = c;
        }
        F += __popc(mb);
        if (__ballot(F >= 32)) {          // coherent: both halves merge together
          int take = F >= 32 ? 32 : F;    // partner half consumes its partial buffer
          unsigned long long vB = (hl < take) ? bufh[hl] : ~0ULL;
          knn_merge32(vL, worst, worst_hi, wd, vB, hl,
                      aX1, aX2, aX4, aX8, aX16, aRev, aW);
          int R = F - take;               // 0..31
          if (hl < R) bufh[hl] = bufh[32 + hl];   // reads 32..62, writes 0..30: disjoint
          F = R;
        }
      }
    }
  }
  if (__ballot(F > 0)) {   // flush remaining (<32) with +inf padding
    unsigned long long vB = (hl < F) ? bufh[hl] : ~0ULL;
    knn_merge32(vL, worst, worst_hi, wd, vB, hl, aX1, aX2, aX4, aX8, aX16, aRev, aW);
  }

  // cross-wave combine: waves (2k, 2k+1) hold lo/hi top-32 for the same queries
  bufh[hl] = vL;
  __syncthreads();
  unsigned long long vB = buf[wv ^ 1][half][hl];
  vL = u64min(vL, bperm64(vB, aRev));            // both sorted asc: reverse-pair min
  vL = selstage(vL, bperm64(vL, aX16), (hl & 16) != 0);
  vL = selstage(vL, bperm64(vL, aX8),  (hl & 8) != 0);
  vL = selstage(vL, bperm64(vL, aX4),  (hl & 4) != 0);
  vL = selstage(vL, bperm64(vL, aX2),  (hl & 2) != 0);
  vL = selstage(vL, bperm64(vL, aX1),  (hl & 1) != 0);
  if (range == 0)
    g_knn[((size_t)q << 5) | hl] = (unsigned short)(vL & 0xFFFF);
}

// ---------------- layer0: gather feats to LDS, MFMA K=96 -> x0 bf16 ----------------
__global__ __launch_bounds__(256) void k_l0(const float* __restrict__ xyz) {
  __shared__ short feats[256][104];   // row 208B: 16B-aligned
  int t = threadIdx.x;
  int p0 = blockIdx.x * 256;
  {
    int p = p0 + t;
    int idx = g_knn[p];
    int s = (p >> 5) & 4095;
    int b = p >> 17;
    const short* src = g_ptb + ((size_t)((b << 14) + idx) << 6);
#pragma unroll
    for (int i = 0; i < 8; i++)
      ((int4*)&feats[t][0])[i] = ((const int4*)src)[i];
    const float* xb = xyz + b * 3 * N_ALL;
    feats[t][64] = f2b(xb[idx] - xb[s]);
    feats[t][65] = f2b(xb[N_ALL + idx] - xb[N_ALL + s]);
    feats[t][66] = f2b(xb[2 * N_ALL + idx] - xb[2 * N_ALL + s]);
#pragma unroll
    for (int c = 67; c < 96; c++) feats[t][c] = 0;
  }
  __syncthreads();
  int lane = t & 63, wv = t >> 6;
  int l15 = lane & 15, quad = lane >> 4;
  bf16x8 A[4][3];
#pragma unroll
  for (int mt = 0; mt < 4; mt++)
#pragma unroll
    for (int kt = 0; kt < 3; kt++)
      A[mt][kt] = *(const bf16x8*)(g_Wb0 + (((mt * 3 + kt) * 64 + lane) << 3));
  f32x4 C[4][4];
#pragma unroll
  for (int mt = 0; mt < 4; mt++)
#pragma unroll
    for (int nt = 0; nt < 4; nt++) C[mt][nt] = 0.f;
#pragma unroll
  for (int kt = 0; kt < 3; kt++)
#pragma unroll
    for (int nt = 0; nt < 4; nt++) {
      bf16x8 B = *(const bf16x8*)(&feats[wv * 64 + nt * 16 + l15][kt * 32 + quad * 8]);
#pragma unroll
      for (int mt = 0; mt < 4; mt++)
        C[mt][nt] = __builtin_amdgcn_mfma_f32_16x16x32_bf16(A[mt][kt], B, C[mt][nt], 0, 0, 0);
    }
#pragma unroll
  for (int mt = 0; mt < 4; mt++)
#pragma unroll
    for (int nt = 0; nt < 4; nt++) {
      int p = p0 + wv * 64 + nt * 16 + l15;
      int c0 = mt * 16 + quad * 4;
      short4 o;
      o.x = f2b(C[mt][nt][0]); o.y = f2b(C[mt][nt][1]);
      o.z = f2b(C[mt][nt][2]); o.w = f2b(C[mt][nt][3]);
      *(short4*)(g_x0b + ((size_t)p << 6) + c0) = o;
    }
}

// ---------------- layer1: BN0+leaky on x0 frags, MFMA K=64 -> x1 bf16 ----------------
__global__ __launch_bounds__(256) void k_l1(const float* __restrict__ g0,
                                            const float* __restrict__ b0) {
  __shared__ float scA[64], shA[64];
  int t = threadIdx.x;
  if (t < 64) {
    float m = g_part0[t] / P_TOTF;
    float v = g_part0[64 + t] / P_TOTF - m * m;
    float sc = g0[t] / sqrtf(v + EPSV);
    scA[t] = sc; shA[t] = b0[t] - m * sc;
  }
  __syncthreads();
  int lane = t & 63, wv = t >> 6;
  int l15 = lane & 15, quad = lane >> 4;
  int p0 = blockIdx.x * 256 + wv * 64;
  float scv[2][8], shv[2][8];
#pragma unroll
  for (int kt = 0; kt < 2; kt++)
#pragma unroll
    for (int j = 0; j < 8; j++) {
      int c = kt * 32 + quad * 8 + j;
      scv[kt][j] = scA[c]; shv[kt][j] = shA[c];
    }
  bf16x8 A[4][2];
#pragma unroll
  for (int mt = 0; mt < 4; mt++)
#pragma unroll
    for (int kt = 0; kt < 2; kt++)
      A[mt][kt] = *(const bf16x8*)(g_Wb1 + (((mt * 2 + kt) * 64 + lane) << 3));
  f32x4 C[4][4];
#pragma unroll
  for (int mt = 0; mt < 4; mt++)
#pragma unroll
    for (int nt = 0; nt < 4; nt++) C[mt][nt] = 0.f;
#pragma unroll
  for (int kt = 0; kt < 2; kt++)
#pragma unroll
    for (int nt = 0; nt < 4; nt++) {
      const short* src = g_x0b + (((size_t)(p0 + nt * 16 + l15)) << 6) + kt * 32 + quad * 8;
      bf16x8 raw = *(const bf16x8*)src;
      bf16x8 B;
#pragma unroll
      for (int j = 0; j < 8; j++) {
        float a = b2f(raw[j]) * scv[kt][j] + shv[kt][j];
        a = fmaxf(a, 0.1f * a);
        B[j] = f2b(a);
      }
#pragma unroll
      for (int mt = 0; mt < 4; mt++)
        C[mt][nt] = __builtin_amdgcn_mfma_f32_16x16x32_bf16(A[mt][kt], B, C[mt][nt], 0, 0, 0);
    }
#pragma unroll
  for (int mt = 0; mt < 4; mt++)
#pragma unroll
    for (int nt = 0; nt < 4; nt++) {
      int p = p0 + nt * 16 + l15;
      int c0 = mt * 16 + quad * 4;
      short4 o;
      o.x = f2b(C[mt][nt][0]); o.y = f2b(C[mt][nt][1]);
      o.z = f2b(C[mt][nt][2]); o.w = f2b(C[mt][nt][3]);
      *(short4*)(g_x1b + ((size_t)p << 6) + c0) = o;
    }
}

// ---------------- layer2: BN1+leaky on x1 frags, MFMA K=64 M=128 -> x2 bf16 ----------------
__global__ __launch_bounds__(256) void k_l2(const float* __restrict__ g1,
                                            const float* __restrict__ b1) {
  __shared__ float scA[64], shA[64];
  int t = threadIdx.x;
  if (t < 64) {
    float m = g_part1[t] / P_TOTF;
    float v = g_part1[64 + t] / P_TOTF - m * m;
    float sc = g1[t] / sqrtf(v + EPSV);
    scA[t] = sc; shA[t] = b1[t] - m * sc;
  }
  __syncthreads();
  int lane = t & 63, wv = t >> 6;
  int l15 = lane & 15, quad = lane >> 4;
  int chh = wv & 1;                      // channel half
  int p0 = blockIdx.x * 128 + (wv >> 1) * 64;
  float scv[2][8], shv[2][8];
#pragma unroll
  for (int kt = 0; kt < 2; kt++)
#pragma unroll
    for (int j = 0; j < 8; j++) {
      int c = kt * 32 + quad * 8 + j;
      scv[kt][j] = scA[c]; shv[kt][j] = shA[c];
    }
  bf16x8 A[4][2];
#pragma unroll
  for (int mt = 0; mt < 4; mt++)
#pragma unroll
    for (int kt = 0; kt < 2; kt++)
      A[mt][kt] = *(const bf16x8*)(g_Wb2 + ((((4 * chh + mt) * 2 + kt) * 64 + lane) << 3));
  f32x4 C[4][4];
#pragma unroll
  for (int mt = 0; mt < 4; mt++)
#pragma unroll
    for (int nt = 0; nt < 4; nt++) C[mt][nt] = 0.f;
#pragma unroll
  for (int kt = 0; kt < 2; kt++)
#pragma unroll
    for (int nt = 0; nt < 4; nt++) {
      const short* src = g_x1b + (((size_t)(p0 + nt * 16 + l15)) << 6) + kt * 32 + quad * 8;
      bf16x8 raw = *(const bf16x8*)src;
      bf16x8 B;
#pragma unroll
      for (int j = 0; j < 8; j++) {
        float a = b2f(raw[j]) * scv[kt][j] + shv[kt][j];
        a = fmaxf(a, 0.1f * a);
        B[j] = f2b(a);
      }
#pragma unroll
      for (int mt = 0; mt < 4; mt++)
        C[mt][nt] = __builtin_amdgcn_mfma_f32_16x16x32_bf16(A[mt][kt], B, C[mt][nt], 0, 0, 0);
    }
#pragma unroll
  for (int mt = 0; mt < 4; mt++)
#pragma unroll
    for (int nt = 0; nt < 4; nt++) {
      int p = p0 + nt * 16 + l15;
      int c0 = (4 * chh + mt) * 16 + quad * 4;
      short4 o;
      o.x = f2b(C[mt][nt][0]); o.y = f2b(C[mt][nt][1]);
      o.z = f2b(C[mt][nt][2]); o.w = f2b(C[mt][nt][3]);
      *(short4*)(g_x2b + ((size_t)p << 7) + c0) = o;
    }
}

// ---------------- streaming stats over bf16 [p][64] (1024 blocks x 256 pts) ----------------
__global__ __launch_bounds__(256) void k_red64(const short* __restrict__ x,
                                               float* __restrict__ part) {
  int t = threadIdx.x;
  int cl = t & 31, pr = t >> 5;
  float s0 = 0.f, s1 = 0.f, q0 = 0.f, q1 = 0.f;
  int pbase = blockIdx.x * 256;
  for (int i = 0; i < 32; i++) {
    int p = pbase + pr + i * 8;
    unsigned d = *(const unsigned*)(x + ((size_t)p << 6) + cl * 2);
    float a = b2f((short)(d & 0xFFFF));
    float b = b2f((short)(d >> 16));
    s0 += a; q0 = fmaf(a, a, q0);
    s1 += b; q1 = fmaf(b, b, q1);
  }
  __shared__ float sm[8][64], sq[8][64];
  sm[pr][cl * 2] = s0; sm[pr][cl * 2 + 1] = s1;
  sq[pr][cl * 2] = q0; sq[pr][cl * 2 + 1] = q1;
  __syncthreads();
  if (t < 64) {
    float S = 0.f, Q = 0.f;
#pragma unroll
    for (int r = 0; r < 8; r++) { S += sm[r][t]; Q += sq[r][t]; }
    atomicAdd(part + t, S); atomicAdd(part + 64 + t, Q);
  }
}

// ---------------- streaming stats over bf16 [p][128] (1024 blocks x 256 pts) ----------------
__global__ __launch_bounds__(256) void k_red128(const short* __restrict__ x,
                                                float* __restrict__ part) {
  int t = threadIdx.x;
  int cl = t & 63, pr = t >> 6;
  float s0 = 0.f, s1 = 0.f, q0 = 0.f, q1 = 0.f;
  int pbase = blockIdx.x * 256;
  for (int i = 0; i < 64; i++) {
    int p = pbase + pr + i * 4;
    unsigned d = *(const unsigned*)(x + ((size_t)p << 7) + cl * 2);
    float a = b2f((short)(d & 0xFFFF));
    float b = b2f((short)(d >> 16));
    s0 += a; q0 = fmaf(a, a, q0);
    s1 += b; q1 = fmaf(b, b, q1);
  }
  __shared__ float sm[4][128], sq[4][128];
  sm[pr][cl * 2] = s0; sm[pr][cl * 2 + 1] = s1;
  sq[pr][cl * 2] = q0; sq[pr][cl * 2 + 1] = q1;
  __syncthreads();
  if (t < 128) {
    float S = 0.f, Q = 0.f;
#pragma unroll
    for (int r = 0; r < 4; r++) { S += sm[r][t]; Q += sq[r][t]; }
    atomicAdd(part + t, S); atomicAdd(part + 128 + t, Q);
  }
}

// ---------------- epilogue: max/min over k from x2, BN2+leaky, write f32 ----------------
__global__ __launch_bounds__(256) void k_epi(const float* __restrict__ g2,
                                             const float* __restrict__ b2,
                                             float* __restrict__ out) {
  __shared__ float scA[128], shA[128];
  int t = threadIdx.x;
  if (t < 128) {
    float m = g_part2[t] / P_TOTF;
    float v = g_part2[128 + t] / P_TOTF - m * m;
    float sc = g2[t] / sqrtf(v + EPSV);
    scA[t] = sc; shA[t] = b2[t] - m * sc;
  }
  __syncthreads();
  int c = t & 127, sl = t >> 7;
  int sg = blockIdx.x * 2 + sl;                  // 0..8191
  size_t base = (((size_t)sg) << 12) + c;        // (sg*32)*128 + c
  float mx = -3.4e38f, mn = 3.4e38f;
#pragma unroll
  for (int k = 0; k < 32; k++) {
    float v = b2f(g_x2b[base + (size_t)k * 128]);
    mx = fmaxf(mx, v); mn = fminf(mn, v);
  }
  float sc = scA[c];
  float a = (sc >= 0.f ? mx : mn) * sc + shA[c];
  a = fmaxf(a, 0.1f * a);
  int b = sg >> 12, s = sg & 4095;
  out[24576 + (((b * 128 + c) << 12) | s)] = a;
}

extern "C" void kernel_launch(void* const* d_in, const int* in_sizes, int n_in,
                              void* d_out, int out_size, void* d_ws, size_t ws_size,
                              hipStream_t stream) {
  (void)in_sizes; (void)n_in; (void)out_size; (void)d_ws; (void)ws_size;
  const float* xyz    = (const float*)d_in[0];
  const float* points = (const float*)d_in[1];
  const float* W0     = (const float*)d_in[2];
  const float* W1     = (const float*)d_in[3];
  const float* W2     = (const float*)d_in[4];
  const float* g0     = (const float*)d_in[5];
  const float* b0     = (const float*)d_in[6];
  const float* g1     = (const float*)d_in[7];
  const float* b1     = (const float*)d_in[8];
  const float* g2     = (const float*)d_in[9];
  const float* b2     = (const float*)d_in[10];
  float* out = (float*)d_out;

  short *x0b, *x1b; float *part0, *part1, *part2;
  hipGetSymbolAddress((void**)&x0b,   HIP_SYMBOL(g_x0b));
  hipGetSymbolAddress((void**)&x1b,   HIP_SYMBOL(g_x1b));
  hipGetSymbolAddress((void**)&part0, HIP_SYMBOL(g_part0));
  hipGetSymbolAddress((void**)&part1, HIP_SYMBOL(g_part1));
  hipGetSymbolAddress((void**)&part2, HIP_SYMBOL(g_part2));

  short *x2b;
  hipGetSymbolAddress((void**)&x2b,   HIP_SYMBOL(g_x2b));

  hipLaunchKernelGGL(k_setup,  dim3(641),  dim3(256), 0, stream, xyz, points, W0, W1, W2, out);
  hipLaunchKernelGGL(k_knn,    dim3(2048), dim3(256), 0, stream);
  hipLaunchKernelGGL(k_l0,     dim3(1024), dim3(256), 0, stream, xyz);
  hipLaunchKernelGGL(k_red64,  dim3(1024), dim3(256), 0, stream, x0b, part0);
  hipLaunchKernelGGL(k_l1,     dim3(1024), dim3(256), 0, stream, g0, b0);
  hipLaunchKernelGGL(k_red64,  dim3(1024), dim3(256), 0, stream, x1b, part1);
  hipLaunchKernelGGL(k_l2,     dim3(2048), dim3(256), 0, stream, g1, b1);
  hipLaunchKernelGGL(k_red128, dim3(1024), dim3(256), 0, stream, x2b, part2);
  hipLaunchKernelGGL(k_epi,    dim3(4096), dim3(256), 0, stream, g2, b2, out);
}

// Round 8
// 330.793 us; speedup vs baseline: 1.1852x; 1.1852x over previous
//
#include <hip/hip_runtime.h>
#include <stdint.h>

#define N_ALL   16384
#define NPOINT  4096
#define KNN_K   32
#define BATCH   2
#define P_TOT   (BATCH*NPOINT*KNN_K)   /* 262144 */
#define P_TOTF  262144.0f
#define EPSV    1e-5f

typedef __attribute__((ext_vector_type(8))) short bf16x8;
typedef __attribute__((ext_vector_type(4))) float f32x4;

// ---- all scratch in module-static device memory; d_ws untouched ----
__device__ unsigned short g_knn[P_TOT];                                   // 512 KB
__device__ __attribute__((aligned(16))) float g_pxyzn[BATCH*N_ALL*4];     // 512 KB (x,y,z,|x|^2)
__device__ __attribute__((aligned(16))) short g_ptb[BATCH*N_ALL*64];      // 4 MB  [b,n][64c] bf16
__device__ __attribute__((aligned(16))) short g_x0b[(size_t)P_TOT*64];    // 32 MB [p][64] bf16
__device__ __attribute__((aligned(16))) short g_x1b[(size_t)P_TOT*64];    // 32 MB
__device__ __attribute__((aligned(16))) short g_x2b[(size_t)P_TOT*128];   // 64 MB
__device__ __attribute__((aligned(16))) short g_Wb0[4*3*64*8];            // swizzled A-frags
__device__ __attribute__((aligned(16))) short g_Wb1[4*2*64*8];
__device__ __attribute__((aligned(16))) short g_Wb2[8*2*64*8];
__device__ float g_part0[128], g_part1[128], g_part2[256];

__device__ __forceinline__ float b2f(short s) {
  union { unsigned u; float f; } v; v.u = ((unsigned)(unsigned short)s) << 16; return v.f;
}
__device__ __forceinline__ short f2b(float f) {
  union { float f; unsigned u; } v; v.f = f;
  unsigned u = v.u;
  u += 0x7FFFu + ((u >> 16) & 1u);
  return (short)(u >> 16);
}
__device__ __forceinline__ unsigned long long bperm64(unsigned long long v, int byteaddr) {
  int lo = __builtin_amdgcn_ds_bpermute(byteaddr, (int)(unsigned)(v & 0xFFFFFFFFULL));
  int hi = __builtin_amdgcn_ds_bpermute(byteaddr, (int)(unsigned)(v >> 32));
  return (((unsigned long long)(unsigned)hi) << 32) | (unsigned)lo;
}
__device__ __forceinline__ unsigned long long u64min(unsigned long long a, unsigned long long b) {
  return a < b ? a : b;
}
// bitonic compare-exchange step: keep min (mx=0) or max (mx=1) of (v, pv)
__device__ __forceinline__ unsigned long long selstage(unsigned long long v,
                                                       unsigned long long pv, bool mx) {
  bool lt = v < pv;
  return (lt != mx) ? v : pv;
}

// sort 32 buffered candidates (vB, one per lane within a 32-lane half) ascending,
// merge lowest-32 of (vL ∪ vB) back into vL (sorted), refresh worst_hi/wd.
__device__ __forceinline__ void knn_merge32(unsigned long long& vL,
                                            unsigned long long& worst,
                                            unsigned& worst_hi, float& wd,
                                            unsigned long long vB, int hl,
                                            int aX1, int aX2, int aX4, int aX8,
                                            int aX16, int aRev, int aW) {
  vB = selstage(vB, bperm64(vB, aX1),  ((hl & 1) != 0) != ((hl & 2) != 0));
  vB = selstage(vB, bperm64(vB, aX2),  ((hl & 2) != 0) != ((hl & 4) != 0));
  vB = selstage(vB, bperm64(vB, aX1),  ((hl & 1) != 0) != ((hl & 4) != 0));
  vB = selstage(vB, bperm64(vB, aX4),  ((hl & 4) != 0) != ((hl & 8) != 0));
  vB = selstage(vB, bperm64(vB, aX2),  ((hl & 2) != 0) != ((hl & 8) != 0));
  vB = selstage(vB, bperm64(vB, aX1),  ((hl & 1) != 0) != ((hl & 8) != 0));
  vB = selstage(vB, bperm64(vB, aX8),  ((hl & 8) != 0) != ((hl & 16) != 0));
  vB = selstage(vB, bperm64(vB, aX4),  ((hl & 4) != 0) != ((hl & 16) != 0));
  vB = selstage(vB, bperm64(vB, aX2),  ((hl & 2) != 0) != ((hl & 16) != 0));
  vB = selstage(vB, bperm64(vB, aX1),  ((hl & 1) != 0) != ((hl & 16) != 0));
  vB = selstage(vB, bperm64(vB, aX16), (hl & 16) != 0);
  vB = selstage(vB, bperm64(vB, aX8),  (hl & 8) != 0);
  vB = selstage(vB, bperm64(vB, aX4),  (hl & 4) != 0);
  vB = selstage(vB, bperm64(vB, aX2),  (hl & 2) != 0);
  vB = selstage(vB, bperm64(vB, aX1),  (hl & 1) != 0);
  // vL asc, vB asc: pair lane i with reversed buffer -> lowest 32 (bitonic), then cleanup
  vL = u64min(vL, bperm64(vB, aRev));
  vL = selstage(vL, bperm64(vL, aX16), (hl & 16) != 0);
  vL = selstage(vL, bperm64(vL, aX8),  (hl & 8) != 0);
  vL = selstage(vL, bperm64(vL, aX4),  (hl & 4) != 0);
  vL = selstage(vL, bperm64(vL, aX2),  (hl & 2) != 0);
  vL = selstage(vL, bperm64(vL, aX1),  (hl & 1) != 0);
  worst = bperm64(vL, aW);
  worst_hi = (unsigned)(worst >> 32);
  unsigned wh = worst_hi;
  unsigned ub = (wh & 0x80000000u) ? (wh ^ 0x80000000u) : ~wh;
  wd = (wh == 0xFFFFFFFFu) ? __builtin_inff() : __uint_as_float(ub);
}

// ---------------- setup: tpose (blk<512) | copy+pack (512..639) | wprep (640) ----------------
__global__ __launch_bounds__(256) void k_setup(const float* __restrict__ xyz,
                                               const float* __restrict__ points,
                                               const float* __restrict__ W0,
                                               const float* __restrict__ W1,
                                               const float* __restrict__ W2,
                                               float* __restrict__ out) {
#pragma clang fp contract(off)
  __shared__ float tile[64][65];
  int blk = blockIdx.x;
  int t = threadIdx.x;
  if (blk < 512) {
    int b  = blk >> 8;
    int n0 = (blk & 255) << 6;
#pragma unroll
    for (int r = 0; r < 16; r++) {
      int lin = r * 256 + t;
      int c = lin >> 6, nn = lin & 63;
      tile[c][nn] = points[((size_t)(b * 64 + c)) * N_ALL + n0 + nn];
    }
    __syncthreads();
#pragma unroll
    for (int r = 0; r < 16; r++) {
      int lin = r * 256 + t;
      int nn = lin >> 6, c = lin & 63;
      g_ptb[((size_t)(b * N_ALL + n0 + nn)) * 64 + c] = f2b(tile[c][nn]);
    }
  } else if (blk < 640) {
    int i = (blk - 512) * 256 + t;   // < 32768
    if (i < 24576) {
      int s = i & 4095;
      int c = (i >> 12) % 3;
      int b = i / 12288;
      out[i] = xyz[(b * 3 + c) * N_ALL + s];
    }
    int b = i >> 14, n = i & 16383;
    const float* xb = xyz + b * 3 * N_ALL;
    float x = xb[n], y = xb[N_ALL + n], z = xb[2 * N_ALL + n];
    float4 p; p.x = x; p.y = y; p.z = z; p.w = x * x + y * y + z * z;
    ((float4*)g_pxyzn)[i] = p;
  } else {
    for (int i = t; i < 4 * 3 * 64 * 8; i += 256) {
      int j = i & 7, lane = (i >> 3) & 63, rest = i >> 9;
      int kt = rest % 3, mt = rest / 3;
      int m = 16 * mt + (lane & 15);
      int k = 32 * kt + (lane >> 4) * 8 + j;
      float v = 0.f;
      if (k < 64) v = W0[m * 67 + 3 + k];
      else if (k < 67) v = W0[m * 67 + (k - 64)];
      g_Wb0[i] = f2b(v);
    }
    for (int i = t; i < 4 * 2 * 64 * 8; i += 256) {
      int j = i & 7, lane = (i >> 3) & 63;
      int kt = (i >> 9) & 1, mt = i >> 10;
      int m = 16 * mt + (lane & 15);
      int k = 32 * kt + (lane >> 4) * 8 + j;
      g_Wb1[i] = f2b(W1[m * 64 + k]);
    }
    for (int i = t; i < 8 * 2 * 64 * 8; i += 256) {
      int j = i & 7, lane = (i >> 3) & 63;
      int kt = (i >> 9) & 1, mt = i >> 10;
      int m = 16 * mt + (lane & 15);
      int k = 32 * kt + (lane >> 4) * 8 + j;
      g_Wb2[i] = f2b(W2[m * 64 + k]);
    }
    if (t < 128) { g_part0[t] = 0.f; g_part1[t] = 0.f; }
    g_part2[t] = 0.f;
  }
}

// ---------------- KNN: split-N 2-way, 2 queries/wave, float gate + survivor-only keys ----------------
__global__ __launch_bounds__(256, 8) void k_knn() {
#pragma clang fp contract(off)
  __shared__ unsigned long long buf[4][2][64];
  int wv = threadIdx.x >> 6;
  int lane = threadIdx.x & 63;
  int half = lane >> 5;            // 0: lanes 0..31 (query A), 1: lanes 32..63 (query B)
  int hl = lane & 31;
  int lanebase = lane & 32;
  unsigned long long* bufh = buf[wv][half];

  int qpair = wv >> 1;             // waves {0,1} share queries, {2,3} share queries
  int range = wv & 1;              // 0: points [0,8192), 1: [8192,16384)
  int q = blockIdx.x * 4 + qpair * 2 + half;   // 0..8191
  int b = q >> 12, s = q & 4095;
  const float4* pb = (const float4*)g_pxyzn + (b << 14);
  float4 qp = pb[s];
  float qx = qp.x, qy = qp.y, qz = qp.z, qn = qp.w;

  // hoisted cross-lane byte addresses (stay within own 32-lane half)
  int aX1  = (lanebase | (hl ^ 1))  << 2;
  int aX2  = (lanebase | (hl ^ 2))  << 2;
  int aX4  = (lanebase | (hl ^ 4))  << 2;
  int aX8  = (lanebase | (hl ^ 8))  << 2;
  int aX16 = (lanebase | (hl ^ 16)) << 2;
  int aRev = (lanebase | (31 - hl)) << 2;
  int aW   = (lanebase | 31)        << 2;

  unsigned long long vL = ~0ULL;      // per-half sorted top-32 (ascending by lane)
  unsigned long long worst = ~0ULL;   // per-lane copy of own half's vL[31]
  unsigned worst_hi = 0xFFFFFFFFu;
  float wd = __builtin_inff();        // worst distance as float (conservative gate)
  int F = 0;                          // buffered-candidate count (uniform within half)

  int base = range << 13;
  for (int n0 = base; n0 < base + 8192; n0 += 128) {
    float4 p0 = pb[n0 + hl];
    float4 p1 = pb[n0 + 32 + hl];
    float4 p2 = pb[n0 + 64 + hl];
    float4 p3 = pb[n0 + 96 + hl];
    float d[4];
    {
      float dt0 = (qx * p0.x + qy * p0.y) + qz * p0.z;   // contract off: exact ref order
      float dt1 = (qx * p1.x + qy * p1.y) + qz * p1.z;
      float dt2 = (qx * p2.x + qy * p2.y) + qz * p2.z;
      float dt3 = (qx * p3.x + qy * p3.y) + qz * p3.z;
      d[0] = __builtin_fmaf(-2.0f, dt0, qn + p0.w);      // == (qn+pn) - 2*dt exactly
      d[1] = __builtin_fmaf(-2.0f, dt1, qn + p1.w);
      d[2] = __builtin_fmaf(-2.0f, dt2, qn + p2.w);
      d[3] = __builtin_fmaf(-2.0f, dt3, qn + p3.w);
    }
    float md = fminf(fminf(d[0], d[1]), fminf(d[2], d[3]));
    if (__ballot(md <= wd)) {
#pragma unroll
      for (int t = 0; t < 4; t++) {
        bool sv = d[t] <= wd;           // float gate: conservative superset of exact u64 test
        unsigned long long bl = __ballot(sv);
        unsigned mb = half ? (unsigned)(bl >> 32) : (unsigned)bl;
        if (sv) {                       // survivors only: build exact u64 key (masked, no branch)
          unsigned u = __float_as_uint(d[t]);
          u ^= ((unsigned)(((int)u) >> 31)) | 0x80000000u;   // order-preserving map
          unsigned long long c = (((unsigned long long)u) << 32)
                               | (unsigned)(n0 + 32 * t + hl);
          bufh[F + __popc(mb & ((1u << hl) - 1u))] = c;
        }
        F += __popc(mb);
        if (__ballot(F >= 32)) {          // coherent: both halves merge together
          int take = F >= 32 ? 32 : F;    // partner half consumes its partial buffer
          unsigned long long vB = (hl < take) ? bufh[hl] : ~0ULL;
          knn_merge32(vL, worst, worst_hi, wd, vB, hl,
                      aX1, aX2, aX4, aX8, aX16, aRev, aW);
          int R = F - take;               // 0..31
          if (hl < R) bufh[hl] = bufh[32 + hl];   // reads 32..62, writes 0..30: disjoint
          F = R;
        }
      }
    }
  }
  if (__ballot(F > 0)) {   // flush remaining (<32) with +inf padding
    unsigned long long vB = (hl < F) ? bufh[hl] : ~0ULL;
    knn_merge32(vL, worst, worst_hi, wd, vB, hl, aX1, aX2, aX4, aX8, aX16, aRev, aW);
  }

  // cross-wave combine: waves (2k, 2k+1) hold lo/hi top-32 for the same queries
  bufh[hl] = vL;
  __syncthreads();
  unsigned long long vB = buf[wv ^ 1][half][hl];
  vL = u64min(vL, bperm64(vB, aRev));            // both sorted asc: reverse-pair min
  vL = selstage(vL, bperm64(vL, aX16), (hl & 16) != 0);
  vL = selstage(vL, bperm64(vL, aX8),  (hl & 8) != 0);
  vL = selstage(vL, bperm64(vL, aX4),  (hl & 4) != 0);
  vL = selstage(vL, bperm64(vL, aX2),  (hl & 2) != 0);
  vL = selstage(vL, bperm64(vL, aX1),  (hl & 1) != 0);
  if (range == 0)
    g_knn[((size_t)q << 5) | hl] = (unsigned short)(vL & 0xFFFF);
}

// ---------------- layer0: gather feats to LDS, MFMA K=96 -> x0 bf16 ----------------
__global__ __launch_bounds__(256) void k_l0(const float* __restrict__ xyz) {
  __shared__ short feats[256][104];   // row 208B: 16B-aligned
  int t = threadIdx.x;
  int p0 = blockIdx.x * 256;
  {
    int p = p0 + t;
    int idx = g_knn[p];
    int s = (p >> 5) & 4095;
    int b = p >> 17;
    const short* src = g_ptb + ((size_t)((b << 14) + idx) << 6);
#pragma unroll
    for (int i = 0; i < 8; i++)
      ((int4*)&feats[t][0])[i] = ((const int4*)src)[i];
    const float* xb = xyz + b * 3 * N_ALL;
    feats[t][64] = f2b(xb[idx] - xb[s]);
    feats[t][65] = f2b(xb[N_ALL + idx] - xb[N_ALL + s]);
    feats[t][66] = f2b(xb[2 * N_ALL + idx] - xb[2 * N_ALL + s]);
#pragma unroll
    for (int c = 67; c < 96; c++) feats[t][c] = 0;
  }
  __syncthreads();
  int lane = t & 63, wv = t >> 6;
  int l15 = lane & 15, quad = lane >> 4;
  bf16x8 A[4][3];
#pragma unroll
  for (int mt = 0; mt < 4; mt++)
#pragma unroll
    for (int kt = 0; kt < 3; kt++)
      A[mt][kt] = *(const bf16x8*)(g_Wb0 + (((mt * 3 + kt) * 64 + lane) << 3));
  f32x4 C[4][4];
#pragma unroll
  for (int mt = 0; mt < 4; mt++)
#pragma unroll
    for (int nt = 0; nt < 4; nt++) C[mt][nt] = 0.f;
#pragma unroll
  for (int kt = 0; kt < 3; kt++)
#pragma unroll
    for (int nt = 0; nt < 4; nt++) {
      bf16x8 B = *(const bf16x8*)(&feats[wv * 64 + nt * 16 + l15][kt * 32 + quad * 8]);
#pragma unroll
      for (int mt = 0; mt < 4; mt++)
        C[mt][nt] = __builtin_amdgcn_mfma_f32_16x16x32_bf16(A[mt][kt], B, C[mt][nt], 0, 0, 0);
    }
#pragma unroll
  for (int mt = 0; mt < 4; mt++)
#pragma unroll
    for (int nt = 0; nt < 4; nt++) {
      int p = p0 + wv * 64 + nt * 16 + l15;
      int c0 = mt * 16 + quad * 4;
      short4 o;
      o.x = f2b(C[mt][nt][0]); o.y = f2b(C[mt][nt][1]);
      o.z = f2b(C[mt][nt][2]); o.w = f2b(C[mt][nt][3]);
      *(short4*)(g_x0b + ((size_t)p << 6) + c0) = o;
    }
}

// ---------------- layer1: BN0+leaky on x0 frags, MFMA K=64 -> x1 bf16 ----------------
__global__ __launch_bounds__(256) void k_l1(const float* __restrict__ g0,
                                            const float* __restrict__ b0) {
  __shared__ float scA[64], shA[64];
  int t = threadIdx.x;
  if (t < 64) {
    float m = g_part0[t] / P_TOTF;
    float v = g_part0[64 + t] / P_TOTF - m * m;
    float sc = g0[t] / sqrtf(v + EPSV);
    scA[t] = sc; shA[t] = b0[t] - m * sc;
  }
  __syncthreads();
  int lane = t & 63, wv = t >> 6;
  int l15 = lane & 15, quad = lane >> 4;
  int p0 = blockIdx.x * 256 + wv * 64;
  float scv[2][8], shv[2][8];
#pragma unroll
  for (int kt = 0; kt < 2; kt++)
#pragma unroll
    for (int j = 0; j < 8; j++) {
      int c = kt * 32 + quad * 8 + j;
      scv[kt][j] = scA[c]; shv[kt][j] = shA[c];
    }
  bf16x8 A[4][2];
#pragma unroll
  for (int mt = 0; mt < 4; mt++)
#pragma unroll
    for (int kt = 0; kt < 2; kt++)
      A[mt][kt] = *(const bf16x8*)(g_Wb1 + (((mt * 2 + kt) * 64 + lane) << 3));
  f32x4 C[4][4];
#pragma unroll
  for (int mt = 0; mt < 4; mt++)
#pragma unroll
    for (int nt = 0; nt < 4; nt++) C[mt][nt] = 0.f;
#pragma unroll
  for (int kt = 0; kt < 2; kt++)
#pragma unroll
    for (int nt = 0; nt < 4; nt++) {
      const short* src = g_x0b + (((size_t)(p0 + nt * 16 + l15)) << 6) + kt * 32 + quad * 8;
      bf16x8 raw = *(const bf16x8*)src;
      bf16x8 B;
#pragma unroll
      for (int j = 0; j < 8; j++) {
        float a = b2f(raw[j]) * scv[kt][j] + shv[kt][j];
        a = fmaxf(a, 0.1f * a);
        B[j] = f2b(a);
      }
#pragma unroll
      for (int mt = 0; mt < 4; mt++)
        C[mt][nt] = __builtin_amdgcn_mfma_f32_16x16x32_bf16(A[mt][kt], B, C[mt][nt], 0, 0, 0);
    }
#pragma unroll
  for (int mt = 0; mt < 4; mt++)
#pragma unroll
    for (int nt = 0; nt < 4; nt++) {
      int p = p0 + nt * 16 + l15;
      int c0 = mt * 16 + quad * 4;
      short4 o;
      o.x = f2b(C[mt][nt][0]); o.y = f2b(C[mt][nt][1]);
      o.z = f2b(C[mt][nt][2]); o.w = f2b(C[mt][nt][3]);
      *(short4*)(g_x1b + ((size_t)p << 6) + c0) = o;
    }
}

// ---------------- layer2: BN1+leaky on x1 frags, MFMA K=64 M=128 -> x2 bf16 ----------------
__global__ __launch_bounds__(256) void k_l2(const float* __restrict__ g1,
                                            const float* __restrict__ b1) {
  __shared__ float scA[64], shA[64];
  int t = threadIdx.x;
  if (t < 64) {
    float m = g_part1[t] / P_TOTF;
    float v = g_part1[64 + t] / P_TOTF - m * m;
    float sc = g1[t] / sqrtf(v + EPSV);
    scA[t] = sc; shA[t] = b1[t] - m * sc;
  }
  __syncthreads();
  int lane = t & 63, wv = t >> 6;
  int l15 = lane & 15, quad = lane >> 4;
  int chh = wv & 1;                      // channel half
  int p0 = blockIdx.x * 128 + (wv >> 1) * 64;
  float scv[2][8], shv[2][8];
#pragma unroll
  for (int kt = 0; kt < 2; kt++)
#pragma unroll
    for (int j = 0; j < 8; j++) {
      int c = kt * 32 + quad * 8 + j;
      scv[kt][j] = scA[c]; shv[kt][j] = shA[c];
    }
  bf16x8 A[4][2];
#pragma unroll
  for (int mt = 0; mt < 4; mt++)
#pragma unroll
    for (int kt = 0; kt < 2; kt++)
      A[mt][kt] = *(const bf16x8*)(g_Wb2 + ((((4 * chh + mt) * 2 + kt) * 64 + lane) << 3));
  f32x4 C[4][4];
#pragma unroll
  for (int mt = 0; mt < 4; mt++)
#pragma unroll
    for (int nt = 0; nt < 4; nt++) C[mt][nt] = 0.f;
#pragma unroll
  for (int kt = 0; kt < 2; kt++)
#pragma unroll
    for (int nt = 0; nt < 4; nt++) {
      const short* src = g_x1b + (((size_t)(p0 + nt * 16 + l15)) << 6) + kt * 32 + quad * 8;
      bf16x8 raw = *(const bf16x8*)src;
      bf16x8 B;
#pragma unroll
      for (int j = 0; j < 8; j++) {
        float a = b2f(raw[j]) * scv[kt][j] + shv[kt][j];
        a = fmaxf(a, 0.1f * a);
        B[j] = f2b(a);
      }
#pragma unroll
      for (int mt = 0; mt < 4; mt++)
        C[mt][nt] = __builtin_amdgcn_mfma_f32_16x16x32_bf16(A[mt][kt], B, C[mt][nt], 0, 0, 0);
    }
#pragma unroll
  for (int mt = 0; mt < 4; mt++)
#pragma unroll
    for (int nt = 0; nt < 4; nt++) {
      int p = p0 + nt * 16 + l15;
      int c0 = (4 * chh + mt) * 16 + quad * 4;
      short4 o;
      o.x = f2b(C[mt][nt][0]); o.y = f2b(C[mt][nt][1]);
      o.z = f2b(C[mt][nt][2]); o.w = f2b(C[mt][nt][3]);
      *(short4*)(g_x2b + ((size_t)p << 7) + c0) = o;
    }
}

// ---------------- streaming stats over bf16 [p][64] ----------------
__global__ __launch_bounds__(256) void k_red64(const short* __restrict__ x,
                                               float* __restrict__ part) {
  int t = threadIdx.x;
  int cl = t & 31, pr = t >> 5;
  float s0 = 0.f, s1 = 0.f, q0 = 0.f, q1 = 0.f;
  int pbase = blockIdx.x * 1024;
  for (int i = 0; i < 128; i++) {
    int p = pbase + pr + i * 8;
    unsigned d = *(const unsigned*)(x + ((size_t)p << 6) + cl * 2);
    float a = b2f((short)(d & 0xFFFF));
    float b = b2f((short)(d >> 16));
    s0 += a; q0 = fmaf(a, a, q0);
    s1 += b; q1 = fmaf(b, b, q1);
  }
  __shared__ float sm[8][64], sq[8][64];
  sm[pr][cl * 2] = s0; sm[pr][cl * 2 + 1] = s1;
  sq[pr][cl * 2] = q0; sq[pr][cl * 2 + 1] = q1;
  __syncthreads();
  if (t < 64) {
    float S = 0.f, Q = 0.f;
#pragma unroll
    for (int r = 0; r < 8; r++) { S += sm[r][t]; Q += sq[r][t]; }
    atomicAdd(part + t, S); atomicAdd(part + 64 + t, Q);
  }
}

// ---------------- streaming stats over bf16 [p][128] ----------------
__global__ __launch_bounds__(256) void k_red128(const short* __restrict__ x,
                                                float* __restrict__ part) {
  int t = threadIdx.x;
  int cl = t & 63, pr = t >> 6;
  float s0 = 0.f, s1 = 0.f, q0 = 0.f, q1 = 0.f;
  int pbase = blockIdx.x * 1024;
  for (int i = 0; i < 256; i++) {
    int p = pbase + pr + i * 4;
    unsigned d = *(const unsigned*)(x + ((size_t)p << 7) + cl * 2);
    float a = b2f((short)(d & 0xFFFF));
    float b = b2f((short)(d >> 16));
    s0 += a; q0 = fmaf(a, a, q0);
    s1 += b; q1 = fmaf(b, b, q1);
  }
  __shared__ float sm[4][128], sq[4][128];
  sm[pr][cl * 2] = s0; sm[pr][cl * 2 + 1] = s1;
  sq[pr][cl * 2] = q0; sq[pr][cl * 2 + 1] = q1;
  __syncthreads();
  if (t < 128) {
    float S = 0.f, Q = 0.f;
#pragma unroll
    for (int r = 0; r < 4; r++) { S += sm[r][t]; Q += sq[r][t]; }
    atomicAdd(part + t, S); atomicAdd(part + 128 + t, Q);
  }
}

// ---------------- epilogue: max/min over k from x2, BN2+leaky, write f32 ----------------
__global__ __launch_bounds__(256) void k_epi(const float* __restrict__ g2,
                                             const float* __restrict__ b2,
                                             float* __restrict__ out) {
  __shared__ float scA[128], shA[128];
  int t = threadIdx.x;
  if (t < 128) {
    float m = g_part2[t] / P_TOTF;
    float v = g_part2[128 + t] / P_TOTF - m * m;
    float sc = g2[t] / sqrtf(v + EPSV);
    scA[t] = sc; shA[t] = b2[t] - m * sc;
  }
  __syncthreads();
  int c = t & 127, sl = t >> 7;
  int sg = blockIdx.x * 2 + sl;                  // 0..8191
  size_t base = (((size_t)sg) << 12) + c;        // (sg*32)*128 + c
  float mx = -3.4e38f, mn = 3.4e38f;
#pragma unroll
  for (int k = 0; k < 32; k++) {
    float v = b2f(g_x2b[base + (size_t)k * 128]);
    mx = fmaxf(mx, v); mn = fminf(mn, v);
  }
  float sc = scA[c];
  float a = (sc >= 0.f ? mx : mn) * sc + shA[c];
  a = fmaxf(a, 0.1f * a);
  int b = sg >> 12, s = sg & 4095;
  out[24576 + (((b * 128 + c) << 12) | s)] = a;
}

extern "C" void kernel_launch(void* const* d_in, const int* in_sizes, int n_in,
                              void* d_out, int out_size, void* d_ws, size_t ws_size,
                              hipStream_t stream) {
  (void)in_sizes; (void)n_in; (void)out_size; (void)d_ws; (void)ws_size;
  const float* xyz    = (const float*)d_in[0];
  const float* points = (const float*)d_in[1];
  const float* W0     = (const float*)d_in[2];
  const float* W1     = (const float*)d_in[3];
  const float* W2     = (const float*)d_in[4];
  const float* g0     = (const float*)d_in[5];
  const float* b0     = (const float*)d_in[6];
  const float* g1     = (const float*)d_in[7];
  const float* b1     = (const float*)d_in[8];
  const float* g2     = (const float*)d_in[9];
  const float* b2     = (const float*)d_in[10];
  float* out = (float*)d_out;

  short *x0b, *x1b, *x2b; float *part0, *part1, *part2;
  hipGetSymbolAddress((void**)&x0b,   HIP_SYMBOL(g_x0b));
  hipGetSymbolAddress((void**)&x1b,   HIP_SYMBOL(g_x1b));
  hipGetSymbolAddress((void**)&x2b,   HIP_SYMBOL(g_x2b));
  hipGetSymbolAddress((void**)&part0, HIP_SYMBOL(g_part0));
  hipGetSymbolAddress((void**)&part1, HIP_SYMBOL(g_part1));
  hipGetSymbolAddress((void**)&part2, HIP_SYMBOL(g_part2));

  hipLaunchKernelGGL(k_setup,  dim3(641),  dim3(256), 0, stream, xyz, points, W0, W1, W2, out);
  hipLaunchKernelGGL(k_knn,    dim3(2048), dim3(256), 0, stream);
  hipLaunchKernelGGL(k_l0,     dim3(1024), dim3(256), 0, stream, xyz);
  hipLaunchKernelGGL(k_red64,  dim3(256),  dim3(256), 0, stream, x0b, part0);
  hipLaunchKernelGGL(k_l1,     dim3(1024), dim3(256), 0, stream, g0, b0);
  hipLaunchKernelGGL(k_red64,  dim3(256),  dim3(256), 0, stream, x1b, part1);
  hipLaunchKernelGGL(k_l2,     dim3(2048), dim3(256), 0, stream, g1, b1);
  hipLaunchKernelGGL(k_red128, dim3(256),  dim3(256), 0, stream, x2b, part2);
  hipLaunchKernelGGL(k_epi,    dim3(4096), dim3(256), 0, stream, g2, b2, out);
}

// Round 9
// 321.494 us; speedup vs baseline: 1.2195x; 1.0289x over previous
//
#include <hip/hip_runtime.h>
#include <hip/hip_bf16.h>
#include <stdint.h>

#define N_ALL   16384
#define NPOINT  4096
#define KNN_K   32
#define BATCH   2
#define P_TOT   (BATCH*NPOINT*KNN_K)   /* 262144 */
#define P_TOTF  262144.0f
#define EPSV    1e-5f

typedef __attribute__((ext_vector_type(8))) short bf16x8;
typedef __attribute__((ext_vector_type(4))) float f32x4;

// ---- all scratch in module-static device memory; d_ws untouched ----
__device__ unsigned short g_knn[P_TOT];                                   // 512 KB
__device__ __attribute__((aligned(16))) float g_pxyzn[BATCH*N_ALL*4];     // 512 KB (x,y,z,|x|^2)
__device__ __attribute__((aligned(16))) short g_ptb[BATCH*N_ALL*64];      // 4 MB  [b,n][64c] bf16
__device__ __attribute__((aligned(16))) short g_x0b[(size_t)P_TOT*64];    // 32 MB [p][64] bf16
__device__ __attribute__((aligned(16))) short g_x1b[(size_t)P_TOT*64];    // 32 MB
__device__ __attribute__((aligned(16))) short g_x2b[(size_t)P_TOT*128];   // 64 MB
__device__ __attribute__((aligned(16))) short g_Wb0[4*3*64*8];            // swizzled A-frags
__device__ __attribute__((aligned(16))) short g_Wb1[4*2*64*8];
__device__ __attribute__((aligned(16))) short g_Wb2[8*2*64*8];
__device__ float g_part0[128], g_part1[128], g_part2[256];

__device__ __forceinline__ float b2f(short s) {
  union { unsigned u; float f; } v; v.u = ((unsigned)(unsigned short)s) << 16; return v.f;
}
__device__ __forceinline__ short f2b(float f) {
  union { float f; unsigned u; } v; v.f = f;
  unsigned u = v.u;
  u += 0x7FFFu + ((u >> 16) & 1u);
  return (short)(u >> 16);
}
// packed f32x2 -> bf16x2 (v_cvt_pk_bf16_f32, RNE — bit-identical to f2b pairs)
__device__ __forceinline__ unsigned pkbf(float a, float b) {
  union { __hip_bfloat162 h; unsigned u; } v;
  v.h = __float22bfloat162_rn(make_float2(a, b));
  return v.u;
}
__device__ __forceinline__ unsigned long long bperm64(unsigned long long v, int byteaddr) {
  int lo = __builtin_amdgcn_ds_bpermute(byteaddr, (int)(unsigned)(v & 0xFFFFFFFFULL));
  int hi = __builtin_amdgcn_ds_bpermute(byteaddr, (int)(unsigned)(v >> 32));
  return (((unsigned long long)(unsigned)hi) << 32) | (unsigned)lo;
}
__device__ __forceinline__ unsigned long long u64min(unsigned long long a, unsigned long long b) {
  return a < b ? a : b;
}
// bitonic compare-exchange step: keep min (mx=0) or max (mx=1) of (v, pv)
__device__ __forceinline__ unsigned long long selstage(unsigned long long v,
                                                       unsigned long long pv, bool mx) {
  bool lt = v < pv;
  return (lt != mx) ? v : pv;
}

// sort 32 buffered candidates (vB, one per lane within a 32-lane half) ascending,
// merge lowest-32 of (vL ∪ vB) back into vL (sorted), refresh worst_hi/wd.
__device__ __forceinline__ void knn_merge32(unsigned long long& vL,
                                            unsigned long long& worst,
                                            unsigned& worst_hi, float& wd,
                                            unsigned long long vB, int hl,
                                            int aX1, int aX2, int aX4, int aX8,
                                            int aX16, int aRev, int aW) {
  vB = selstage(vB, bperm64(vB, aX1),  ((hl & 1) != 0) != ((hl & 2) != 0));
  vB = selstage(vB, bperm64(vB, aX2),  ((hl & 2) != 0) != ((hl & 4) != 0));
  vB = selstage(vB, bperm64(vB, aX1),  ((hl & 1) != 0) != ((hl & 4) != 0));
  vB = selstage(vB, bperm64(vB, aX4),  ((hl & 4) != 0) != ((hl & 8) != 0));
  vB = selstage(vB, bperm64(vB, aX2),  ((hl & 2) != 0) != ((hl & 8) != 0));
  vB = selstage(vB, bperm64(vB, aX1),  ((hl & 1) != 0) != ((hl & 8) != 0));
  vB = selstage(vB, bperm64(vB, aX8),  ((hl & 8) != 0) != ((hl & 16) != 0));
  vB = selstage(vB, bperm64(vB, aX4),  ((hl & 4) != 0) != ((hl & 16) != 0));
  vB = selstage(vB, bperm64(vB, aX2),  ((hl & 2) != 0) != ((hl & 16) != 0));
  vB = selstage(vB, bperm64(vB, aX1),  ((hl & 1) != 0) != ((hl & 16) != 0));
  vB = selstage(vB, bperm64(vB, aX16), (hl & 16) != 0);
  vB = selstage(vB, bperm64(vB, aX8),  (hl & 8) != 0);
  vB = selstage(vB, bperm64(vB, aX4),  (hl & 4) != 0);
  vB = selstage(vB, bperm64(vB, aX2),  (hl & 2) != 0);
  vB = selstage(vB, bperm64(vB, aX1),  (hl & 1) != 0);
  // vL asc, vB asc: pair lane i with reversed buffer -> lowest 32 (bitonic), then cleanup
  vL = u64min(vL, bperm64(vB, aRev));
  vL = selstage(vL, bperm64(vL, aX16), (hl & 16) != 0);
  vL = selstage(vL, bperm64(vL, aX8),  (hl & 8) != 0);
  vL = selstage(vL, bperm64(vL, aX4),  (hl & 4) != 0);
  vL = selstage(vL, bperm64(vL, aX2),  (hl & 2) != 0);
  vL = selstage(vL, bperm64(vL, aX1),  (hl & 1) != 0);
  worst = bperm64(vL, aW);
  worst_hi = (unsigned)(worst >> 32);
  unsigned wh = worst_hi;
  unsigned ub = (wh & 0x80000000u) ? (wh ^ 0x80000000u) : ~wh;
  wd = (wh == 0xFFFFFFFFu) ? __builtin_inff() : __uint_as_float(ub);
}

// ---------------- setup: tpose (blk<512) | copy+pack (512..639) | wprep (640) ----------------
__global__ __launch_bounds__(256) void k_setup(const float* __restrict__ xyz,
                                               const float* __restrict__ points,
                                               const float* __restrict__ W0,
                                               const float* __restrict__ W1,
                                               const float* __restrict__ W2,
                                               float* __restrict__ out) {
#pragma clang fp contract(off)
  __shared__ float tile[64][65];
  int blk = blockIdx.x;
  int t = threadIdx.x;
  if (blk < 512) {
    int b  = blk >> 8;
    int n0 = (blk & 255) << 6;
#pragma unroll
    for (int r = 0; r < 16; r++) {
      int lin = r * 256 + t;
      int c = lin >> 6, nn = lin & 63;
      tile[c][nn] = points[((size_t)(b * 64 + c)) * N_ALL + n0 + nn];
    }
    __syncthreads();
#pragma unroll
    for (int r = 0; r < 16; r++) {
      int lin = r * 256 + t;
      int nn = lin >> 6, c = lin & 63;
      g_ptb[((size_t)(b * N_ALL + n0 + nn)) * 64 + c] = f2b(tile[c][nn]);
    }
  } else if (blk < 640) {
    int i = (blk - 512) * 256 + t;   // < 32768
    if (i < 24576) {
      int s = i & 4095;
      int c = (i >> 12) % 3;
      int b = i / 12288;
      out[i] = xyz[(b * 3 + c) * N_ALL + s];
    }
    int b = i >> 14, n = i & 16383;
    const float* xb = xyz + b * 3 * N_ALL;
    float x = xb[n], y = xb[N_ALL + n], z = xb[2 * N_ALL + n];
    float4 p; p.x = x; p.y = y; p.z = z; p.w = x * x + y * y + z * z;
    ((float4*)g_pxyzn)[i] = p;
  } else {
    for (int i = t; i < 4 * 3 * 64 * 8; i += 256) {
      int j = i & 7, lane = (i >> 3) & 63, rest = i >> 9;
      int kt = rest % 3, mt = rest / 3;
      int m = 16 * mt + (lane & 15);
      int k = 32 * kt + (lane >> 4) * 8 + j;
      float v = 0.f;
      if (k < 64) v = W0[m * 67 + 3 + k];
      else if (k < 67) v = W0[m * 67 + (k - 64)];
      g_Wb0[i] = f2b(v);
    }
    for (int i = t; i < 4 * 2 * 64 * 8; i += 256) {
      int j = i & 7, lane = (i >> 3) & 63;
      int kt = (i >> 9) & 1, mt = i >> 10;
      int m = 16 * mt + (lane & 15);
      int k = 32 * kt + (lane >> 4) * 8 + j;
      g_Wb1[i] = f2b(W1[m * 64 + k]);
    }
    for (int i = t; i < 8 * 2 * 64 * 8; i += 256) {
      int j = i & 7, lane = (i >> 3) & 63;
      int kt = (i >> 9) & 1, mt = i >> 10;
      int m = 16 * mt + (lane & 15);
      int k = 32 * kt + (lane >> 4) * 8 + j;
      g_Wb2[i] = f2b(W2[m * 64 + k]);
    }
    if (t < 128) { g_part0[t] = 0.f; g_part1[t] = 0.f; }
    g_part2[t] = 0.f;
  }
}

// ---------------- KNN: split-N 2-way, 2 queries/wave, float gate + survivor-only keys ----------------
__global__ __launch_bounds__(256, 8) void k_knn() {
#pragma clang fp contract(off)
  __shared__ unsigned long long buf[4][2][64];
  int wv = threadIdx.x >> 6;
  int lane = threadIdx.x & 63;
  int half = lane >> 5;            // 0: lanes 0..31 (query A), 1: lanes 32..63 (query B)
  int hl = lane & 31;
  int lanebase = lane & 32;
  unsigned long long* bufh = buf[wv][half];

  int qpair = wv >> 1;             // waves {0,1} share queries, {2,3} share queries
  int range = wv & 1;              // 0: points [0,8192), 1: [8192,16384)
  int q = blockIdx.x * 4 + qpair * 2 + half;   // 0..8191
  int b = q >> 12, s = q & 4095;
  const float4* pb = (const float4*)g_pxyzn + (b << 14);
  float4 qp = pb[s];
  float qx = qp.x, qy = qp.y, qz = qp.z, qn = qp.w;

  // hoisted cross-lane byte addresses (stay within own 32-lane half)
  int aX1  = (lanebase | (hl ^ 1))  << 2;
  int aX2  = (lanebase | (hl ^ 2))  << 2;
  int aX4  = (lanebase | (hl ^ 4))  << 2;
  int aX8  = (lanebase | (hl ^ 8))  << 2;
  int aX16 = (lanebase | (hl ^ 16)) << 2;
  int aRev = (lanebase | (31 - hl)) << 2;
  int aW   = (lanebase | 31)        << 2;

  unsigned long long vL = ~0ULL;      // per-half sorted top-32 (ascending by lane)
  unsigned long long worst = ~0ULL;   // per-lane copy of own half's vL[31]
  unsigned worst_hi = 0xFFFFFFFFu;
  float wd = __builtin_inff();        // worst distance as float (conservative gate)
  int F = 0;                          // buffered-candidate count (uniform within half)

  int base = range << 13;
  for (int n0 = base; n0 < base + 8192; n0 += 128) {
    float4 p0 = pb[n0 + hl];
    float4 p1 = pb[n0 + 32 + hl];
    float4 p2 = pb[n0 + 64 + hl];
    float4 p3 = pb[n0 + 96 + hl];
    float d[4];
    {
      float dt0 = (qx * p0.x + qy * p0.y) + qz * p0.z;   // contract off: exact ref order
      float dt1 = (qx * p1.x + qy * p1.y) + qz * p1.z;
      float dt2 = (qx * p2.x + qy * p2.y) + qz * p2.z;
      float dt3 = (qx * p3.x + qy * p3.y) + qz * p3.z;
      d[0] = __builtin_fmaf(-2.0f, dt0, qn + p0.w);      // == (qn+pn) - 2*dt exactly
      d[1] = __builtin_fmaf(-2.0f, dt1, qn + p1.w);
      d[2] = __builtin_fmaf(-2.0f, dt2, qn + p2.w);
      d[3] = __builtin_fmaf(-2.0f, dt3, qn + p3.w);
    }
    float md = fminf(fminf(d[0], d[1]), fminf(d[2], d[3]));
    if (__ballot(md <= wd)) {
#pragma unroll
      for (int t = 0; t < 4; t++) {
        bool sv = d[t] <= wd;           // float gate: conservative superset of exact u64 test
        unsigned long long bl = __ballot(sv);
        unsigned mb = half ? (unsigned)(bl >> 32) : (unsigned)bl;
        if (sv) {                       // survivors only: build exact u64 key (masked, no branch)
          unsigned u = __float_as_uint(d[t]);
          u ^= ((unsigned)(((int)u) >> 31)) | 0x80000000u;   // order-preserving map
          unsigned long long c = (((unsigned long long)u) << 32)
                               | (unsigned)(n0 + 32 * t + hl);
          bufh[F + __popc(mb & ((1u << hl) - 1u))] = c;
        }
        F += __popc(mb);
        if (__ballot(F >= 32)) {          // coherent: both halves merge together
          int take = F >= 32 ? 32 : F;    // partner half consumes its partial buffer
          unsigned long long vB = (hl < take) ? bufh[hl] : ~0ULL;
          knn_merge32(vL, worst, worst_hi, wd, vB, hl,
                      aX1, aX2, aX4, aX8, aX16, aRev, aW);
          int R = F - take;               // 0..31
          if (hl < R) bufh[hl] = bufh[32 + hl];   // reads 32..62, writes 0..30: disjoint
          F = R;
        }
      }
    }
  }
  if (__ballot(F > 0)) {   // flush remaining (<32) with +inf padding
    unsigned long long vB = (hl < F) ? bufh[hl] : ~0ULL;
    knn_merge32(vL, worst, worst_hi, wd, vB, hl, aX1, aX2, aX4, aX8, aX16, aRev, aW);
  }

  // cross-wave combine: waves (2k, 2k+1) hold lo/hi top-32 for the same queries
  bufh[hl] = vL;
  __syncthreads();
  unsigned long long vB = buf[wv ^ 1][half][hl];
  vL = u64min(vL, bperm64(vB, aRev));            // both sorted asc: reverse-pair min
  vL = selstage(vL, bperm64(vL, aX16), (hl & 16) != 0);
  vL = selstage(vL, bperm64(vL, aX8),  (hl & 8) != 0);
  vL = selstage(vL, bperm64(vL, aX4),  (hl & 4) != 0);
  vL = selstage(vL, bperm64(vL, aX2),  (hl & 2) != 0);
  vL = selstage(vL, bperm64(vL, aX1),  (hl & 1) != 0);
  if (range == 0)
    g_knn[((size_t)q << 5) | hl] = (unsigned short)(vL & 0xFFFF);
}

// ---------------- layer0: gather feats to LDS, MFMA K=96 -> x0 bf16 ----------------
__global__ __launch_bounds__(256) void k_l0(const float* __restrict__ xyz) {
  __shared__ short feats[256][104];   // row 208B: 16B-aligned
  int t = threadIdx.x;
  int p0 = blockIdx.x * 256;
  {
    int p = p0 + t;
    int idx = g_knn[p];
    int s = (p >> 5) & 4095;
    int b = p >> 17;
    const short* src = g_ptb + ((size_t)((b << 14) + idx) << 6);
#pragma unroll
    for (int i = 0; i < 8; i++)
      ((int4*)&feats[t][0])[i] = ((const int4*)src)[i];
    const float* xb = xyz + b * 3 * N_ALL;
    feats[t][64] = f2b(xb[idx] - xb[s]);
    feats[t][65] = f2b(xb[N_ALL + idx] - xb[N_ALL + s]);
    feats[t][66] = f2b(xb[2 * N_ALL + idx] - xb[2 * N_ALL + s]);
#pragma unroll
    for (int c = 67; c < 96; c++) feats[t][c] = 0;
  }
  __syncthreads();
  int lane = t & 63, wv = t >> 6;
  int l15 = lane & 15, quad = lane >> 4;
  bf16x8 A[4][3];
#pragma unroll
  for (int mt = 0; mt < 4; mt++)
#pragma unroll
    for (int kt = 0; kt < 3; kt++)
      A[mt][kt] = *(const bf16x8*)(g_Wb0 + (((mt * 3 + kt) * 64 + lane) << 3));
  f32x4 C[4][4];
#pragma unroll
  for (int mt = 0; mt < 4; mt++)
#pragma unroll
    for (int nt = 0; nt < 4; nt++) C[mt][nt] = 0.f;
#pragma unroll
  for (int kt = 0; kt < 3; kt++)
#pragma unroll
    for (int nt = 0; nt < 4; nt++) {
      bf16x8 B = *(const bf16x8*)(&feats[wv * 64 + nt * 16 + l15][kt * 32 + quad * 8]);
#pragma unroll
      for (int mt = 0; mt < 4; mt++)
        C[mt][nt] = __builtin_amdgcn_mfma_f32_16x16x32_bf16(A[mt][kt], B, C[mt][nt], 0, 0, 0);
    }
#pragma unroll
  for (int mt = 0; mt < 4; mt++)
#pragma unroll
    for (int nt = 0; nt < 4; nt++) {
      int p = p0 + wv * 64 + nt * 16 + l15;
      int c0 = mt * 16 + quad * 4;
      uint2 o;
      o.x = pkbf(C[mt][nt][0], C[mt][nt][1]);
      o.y = pkbf(C[mt][nt][2], C[mt][nt][3]);
      *(uint2*)(g_x0b + ((size_t)p << 6) + c0) = o;
    }
}

// ---------------- layer1: BN0+leaky on x0 frags, MFMA K=64 -> x1 bf16 ----------------
__global__ __launch_bounds__(256) void k_l1(const float* __restrict__ g0,
                                            const float* __restrict__ b0) {
  __shared__ float scA[64], shA[64];
  int t = threadIdx.x;
  if (t < 64) {
    float m = g_part0[t] / P_TOTF;
    float v = g_part0[64 + t] / P_TOTF - m * m;
    float sc = g0[t] / sqrtf(v + EPSV);
    scA[t] = sc; shA[t] = b0[t] - m * sc;
  }
  __syncthreads();
  int lane = t & 63, wv = t >> 6;
  int l15 = lane & 15, quad = lane >> 4;
  int p0 = blockIdx.x * 256 + wv * 64;
  float scv[2][8], shv[2][8];
#pragma unroll
  for (int kt = 0; kt < 2; kt++)
#pragma unroll
    for (int j = 0; j < 8; j++) {
      int c = kt * 32 + quad * 8 + j;
      scv[kt][j] = scA[c]; shv[kt][j] = shA[c];
    }
  bf16x8 A[4][2];
#pragma unroll
  for (int mt = 0; mt < 4; mt++)
#pragma unroll
    for (int kt = 0; kt < 2; kt++)
      A[mt][kt] = *(const bf16x8*)(g_Wb1 + (((mt * 2 + kt) * 64 + lane) << 3));
  f32x4 C[4][4];
#pragma unroll
  for (int mt = 0; mt < 4; mt++)
#pragma unroll
    for (int nt = 0; nt < 4; nt++) C[mt][nt] = 0.f;
#pragma unroll
  for (int kt = 0; kt < 2; kt++)
#pragma unroll
    for (int nt = 0; nt < 4; nt++) {
      const short* src = g_x0b + (((size_t)(p0 + nt * 16 + l15)) << 6) + kt * 32 + quad * 8;
      uint4 raw = *(const uint4*)src;
      bf16x8 B;
      unsigned* Bu = (unsigned*)&B;
      unsigned ru[4] = {raw.x, raw.y, raw.z, raw.w};
#pragma unroll
      for (int jj = 0; jj < 4; jj++) {
        float lo = __uint_as_float(ru[jj] << 16);
        float hi = __uint_as_float(ru[jj] & 0xFFFF0000u);
        float a0 = lo * scv[kt][2*jj]   + shv[kt][2*jj];
        float a1 = hi * scv[kt][2*jj+1] + shv[kt][2*jj+1];
        a0 = fmaxf(a0, 0.1f * a0);
        a1 = fmaxf(a1, 0.1f * a1);
        Bu[jj] = pkbf(a0, a1);
      }
#pragma unroll
      for (int mt = 0; mt < 4; mt++)
        C[mt][nt] = __builtin_amdgcn_mfma_f32_16x16x32_bf16(A[mt][kt], B, C[mt][nt], 0, 0, 0);
    }
#pragma unroll
  for (int mt = 0; mt < 4; mt++)
#pragma unroll
    for (int nt = 0; nt < 4; nt++) {
      int p = p0 + nt * 16 + l15;
      int c0 = mt * 16 + quad * 4;
      uint2 o;
      o.x = pkbf(C[mt][nt][0], C[mt][nt][1]);
      o.y = pkbf(C[mt][nt][2], C[mt][nt][3]);
      *(uint2*)(g_x1b + ((size_t)p << 6) + c0) = o;
    }
}

// ---------------- layer2: BN1+leaky on x1 frags, MFMA K=64 M=128 -> x2 bf16 ----------------
__global__ __launch_bounds__(256) void k_l2(const float* __restrict__ g1,
                                            const float* __restrict__ b1) {
  __shared__ float scA[64], shA[64];
  int t = threadIdx.x;
  if (t < 64) {
    float m = g_part1[t] / P_TOTF;
    float v = g_part1[64 + t] / P_TOTF - m * m;
    float sc = g1[t] / sqrtf(v + EPSV);
    scA[t] = sc; shA[t] = b1[t] - m * sc;
  }
  __syncthreads();
  int lane = t & 63, wv = t >> 6;
  int l15 = lane & 15, quad = lane >> 4;
  int chh = wv & 1;                      // channel half
  int p0 = blockIdx.x * 128 + (wv >> 1) * 64;
  float scv[2][8], shv[2][8];
#pragma unroll
  for (int kt = 0; kt < 2; kt++)
#pragma unroll
    for (int j = 0; j < 8; j++) {
      int c = kt * 32 + quad * 8 + j;
      scv[kt][j] = scA[c]; shv[kt][j] = shA[c];
    }
  bf16x8 A[4][2];
#pragma unroll
  for (int mt = 0; mt < 4; mt++)
#pragma unroll
    for (int kt = 0; kt < 2; kt++)
      A[mt][kt] = *(const bf16x8*)(g_Wb2 + ((((4 * chh + mt) * 2 + kt) * 64 + lane) << 3));
  f32x4 C[4][4];
#pragma unroll
  for (int mt = 0; mt < 4; mt++)
#pragma unroll
    for (int nt = 0; nt < 4; nt++) C[mt][nt] = 0.f;
#pragma unroll
  for (int kt = 0; kt < 2; kt++)
#pragma unroll
    for (int nt = 0; nt < 4; nt++) {
      const short* src = g_x1b + (((size_t)(p0 + nt * 16 + l15)) << 6) + kt * 32 + quad * 8;
      uint4 raw = *(const uint4*)src;
      bf16x8 B;
      unsigned* Bu = (unsigned*)&B;
      unsigned ru[4] = {raw.x, raw.y, raw.z, raw.w};
#pragma unroll
      for (int jj = 0; jj < 4; jj++) {
        float lo = __uint_as_float(ru[jj] << 16);
        float hi = __uint_as_float(ru[jj] & 0xFFFF0000u);
        float a0 = lo * scv[kt][2*jj]   + shv[kt][2*jj];
        float a1 = hi * scv[kt][2*jj+1] + shv[kt][2*jj+1];
        a0 = fmaxf(a0, 0.1f * a0);
        a1 = fmaxf(a1, 0.1f * a1);
        Bu[jj] = pkbf(a0, a1);
      }
#pragma unroll
      for (int mt = 0; mt < 4; mt++)
        C[mt][nt] = __builtin_amdgcn_mfma_f32_16x16x32_bf16(A[mt][kt], B, C[mt][nt], 0, 0, 0);
    }
#pragma unroll
  for (int mt = 0; mt < 4; mt++)
#pragma unroll
    for (int nt = 0; nt < 4; nt++) {
      int p = p0 + nt * 16 + l15;
      int c0 = (4 * chh + mt) * 16 + quad * 4;
      uint2 o;
      o.x = pkbf(C[mt][nt][0], C[mt][nt][1]);
      o.y = pkbf(C[mt][nt][2], C[mt][nt][3]);
      *(uint2*)(g_x2b + ((size_t)p << 7) + c0) = o;
    }
}

// ---------------- streaming stats over bf16 [p][64] ----------------
__global__ __launch_bounds__(256) void k_red64(const short* __restrict__ x,
                                               float* __restrict__ part) {
  int t = threadIdx.x;
  int cl = t & 31, pr = t >> 5;
  float s0 = 0.f, s1 = 0.f, q0 = 0.f, q1 = 0.f;
  int pbase = blockIdx.x * 1024;
  for (int i = 0; i < 128; i++) {
    int p = pbase + pr + i * 8;
    unsigned d = *(const unsigned*)(x + ((size_t)p << 6) + cl * 2);
    float a = b2f((short)(d & 0xFFFF));
    float b = b2f((short)(d >> 16));
    s0 += a; q0 = fmaf(a, a, q0);
    s1 += b; q1 = fmaf(b, b, q1);
  }
  __shared__ float sm[8][64], sq[8][64];
  sm[pr][cl * 2] = s0; sm[pr][cl * 2 + 1] = s1;
  sq[pr][cl * 2] = q0; sq[pr][cl * 2 + 1] = q1;
  __syncthreads();
  if (t < 64) {
    float S = 0.f, Q = 0.f;
#pragma unroll
    for (int r = 0; r < 8; r++) { S += sm[r][t]; Q += sq[r][t]; }
    atomicAdd(part + t, S); atomicAdd(part + 64 + t, Q);
  }
}

// ---------------- streaming stats over bf16 [p][128] ----------------
__global__ __launch_bounds__(256) void k_red128(const short* __restrict__ x,
                                                float* __restrict__ part) {
  int t = threadIdx.x;
  int cl = t & 63, pr = t >> 6;
  float s0 = 0.f, s1 = 0.f, q0 = 0.f, q1 = 0.f;
  int pbase = blockIdx.x * 1024;
  for (int i = 0; i < 256; i++) {
    int p = pbase + pr + i * 4;
    unsigned d = *(const unsigned*)(x + ((size_t)p << 7) + cl * 2);
    float a = b2f((short)(d & 0xFFFF));
    float b = b2f((short)(d >> 16));
    s0 += a; q0 = fmaf(a, a, q0);
    s1 += b; q1 = fmaf(b, b, q1);
  }
  __shared__ float sm[4][128], sq[4][128];
  sm[pr][cl * 2] = s0; sm[pr][cl * 2 + 1] = s1;
  sq[pr][cl * 2] = q0; sq[pr][cl * 2 + 1] = q1;
  __syncthreads();
  if (t < 128) {
    float S = 0.f, Q = 0.f;
#pragma unroll
    for (int r = 0; r < 4; r++) { S += sm[r][t]; Q += sq[r][t]; }
    atomicAdd(part + t, S); atomicAdd(part + 128 + t, Q);
  }
}

// ---------------- epilogue: max/min over k from x2, BN2+leaky, coalesced r/w ----------------
// block covers 16 consecutive s-groups; threads read channel PAIRS (uint, 256B/wave);
// LDS-staged transpose so writes emit full 64B lines (float4, 16 consecutive s per c).
__global__ __launch_bounds__(256) void k_epi(const float* __restrict__ g2,
                                             const float* __restrict__ b2,
                                             float* __restrict__ out) {
  __shared__ float scA[128], shA[128];
  __shared__ float res[16][132];
  int t = threadIdx.x;
  if (t < 128) {
    float m = g_part2[t] / P_TOTF;
    float v = g_part2[128 + t] / P_TOTF - m * m;
    float sc = g2[t] / sqrtf(v + EPSV);
    scA[t] = sc; shA[t] = b2[t] - m * sc;
  }
  __syncthreads();
  int cp = t & 63, sl = t >> 6;        // channels 2cp,2cp+1 ; sl in 0..3
  int c0 = cp * 2, c1 = c0 + 1;
  float sc0 = scA[c0], sh0 = shA[c0];
  float sc1 = scA[c1], sh1 = shA[c1];
  int sg0 = blockIdx.x * 16;
  for (int it = 0; it < 4; it++) {
    int sgl = sl * 4 + it;             // 0..15, each once per block
    size_t pbase = ((size_t)(sg0 + sgl)) << 5;   // point base = sg*32
    float mx0 = -3.4e38f, mn0 = 3.4e38f, mx1 = -3.4e38f, mn1 = 3.4e38f;
#pragma unroll
    for (int k = 0; k < 32; k++) {
      unsigned u = *(const unsigned*)(g_x2b + ((pbase + k) << 7) + cp * 2);
      float v0 = __uint_as_float(u << 16);
      float v1 = __uint_as_float(u & 0xFFFF0000u);
      mx0 = fmaxf(mx0, v0); mn0 = fminf(mn0, v0);
      mx1 = fmaxf(mx1, v1); mn1 = fminf(mn1, v1);
    }
    float a0 = (sc0 >= 0.f ? mx0 : mn0) * sc0 + sh0; a0 = fmaxf(a0, 0.1f * a0);
    float a1 = (sc1 >= 0.f ? mx1 : mn1) * sc1 + sh1; a1 = fmaxf(a1, 0.1f * a1);
    res[sgl][c0] = a0; res[sgl][c1] = a1;
  }
  __syncthreads();
  int b = sg0 >> 12, s0 = sg0 & 4095;   // block never straddles b (4096 % 16 == 0)
#pragma unroll
  for (int w = 0; w < 2; w++) {
    int fidx = t * 2 + w;               // 0..511
    int c = fidx >> 2, qi = fidx & 3;
    float4 o;
    o.x = res[qi * 4 + 0][c];
    o.y = res[qi * 4 + 1][c];
    o.z = res[qi * 4 + 2][c];
    o.w = res[qi * 4 + 3][c];
    *(float4*)(out + 24576 + (((size_t)(b * 128 + c)) << 12) + s0 + qi * 4) = o;
  }
}

extern "C" void kernel_launch(void* const* d_in, const int* in_sizes, int n_in,
                              void* d_out, int out_size, void* d_ws, size_t ws_size,
                              hipStream_t stream) {
  (void)in_sizes; (void)n_in; (void)out_size; (void)d_ws; (void)ws_size;
  const float* xyz    = (const float*)d_in[0];
  const float* points = (const float*)d_in[1];
  const float* W0     = (const float*)d_in[2];
  const float* W1     = (const float*)d_in[3];
  const float* W2     = (const float*)d_in[4];
  const float* g0     = (const float*)d_in[5];
  const float* b0     = (const float*)d_in[6];
  const float* g1     = (const float*)d_in[7];
  const float* b1     = (const float*)d_in[8];
  const float* g2     = (const float*)d_in[9];
  const float* b2     = (const float*)d_in[10];
  float* out = (float*)d_out;

  short *x0b, *x1b, *x2b; float *part0, *part1, *part2;
  hipGetSymbolAddress((void**)&x0b,   HIP_SYMBOL(g_x0b));
  hipGetSymbolAddress((void**)&x1b,   HIP_SYMBOL(g_x1b));
  hipGetSymbolAddress((void**)&x2b,   HIP_SYMBOL(g_x2b));
  hipGetSymbolAddress((void**)&part0, HIP_SYMBOL(g_part0));
  hipGetSymbolAddress((void**)&part1, HIP_SYMBOL(g_part1));
  hipGetSymbolAddress((void**)&part2, HIP_SYMBOL(g_part2));

  hipLaunchKernelGGL(k_setup,  dim3(641),  dim3(256), 0, stream, xyz, points, W0, W1, W2, out);
  hipLaunchKernelGGL(k_knn,    dim3(2048), dim3(256), 0, stream);
  hipLaunchKernelGGL(k_l0,     dim3(1024), dim3(256), 0, stream, xyz);
  hipLaunchKernelGGL(k_red64,  dim3(256),  dim3(256), 0, stream, x0b, part0);
  hipLaunchKernelGGL(k_l1,     dim3(1024), dim3(256), 0, stream, g0, b0);
  hipLaunchKernelGGL(k_red64,  dim3(256),  dim3(256), 0, stream, x1b, part1);
  hipLaunchKernelGGL(k_l2,     dim3(2048), dim3(256), 0, stream, g1, b1);
  hipLaunchKernelGGL(k_red128, dim3(256),  dim3(256), 0, stream, x2b, part2);
  hipLaunchKernelGGL(k_epi,    dim3(512),  dim3(256), 0, stream, g2, b2, out);
}

// Round 10
// 312.070 us; speedup vs baseline: 1.2563x; 1.0302x over previous
//
#include <hip/hip_runtime.h>
#include <hip/hip_bf16.h>
#include <stdint.h>

#define N_ALL   16384
#define NPOINT  4096
#define KNN_K   32
#define BATCH   2
#define P_TOT   (BATCH*NPOINT*KNN_K)   /* 262144 */
#define P_TOTF  262144.0f
#define EPSV    1e-5f

typedef __attribute__((ext_vector_type(8))) short bf16x8;
typedef __attribute__((ext_vector_type(4))) float f32x4;

// ---- all scratch in module-static device memory; d_ws untouched ----
__device__ unsigned short g_knn[P_TOT];                                   // 512 KB
__device__ __attribute__((aligned(16))) float g_pxyzn[BATCH*N_ALL*4];     // 512 KB (x,y,z,|x|^2)
__device__ __attribute__((aligned(16))) short g_ptb[BATCH*N_ALL*64];      // 4 MB  [b,n][64c] bf16
__device__ __attribute__((aligned(16))) short g_x0b[(size_t)P_TOT*64];    // 32 MB [p][64] bf16
__device__ __attribute__((aligned(16))) short g_x1b[(size_t)P_TOT*64];    // 32 MB
__device__ __attribute__((aligned(16))) short g_x2b[(size_t)P_TOT*128];   // 64 MB
__device__ __attribute__((aligned(16))) float g_mx[(size_t)BATCH*NPOINT*128];  // 4 MB
__device__ __attribute__((aligned(16))) float g_mn[(size_t)BATCH*NPOINT*128];  // 4 MB
__device__ __attribute__((aligned(16))) short g_Wb0[4*3*64*8];            // swizzled A-frags
__device__ __attribute__((aligned(16))) short g_Wb1[4*2*64*8];
__device__ __attribute__((aligned(16))) short g_Wb2[8*2*64*8];
__device__ float g_part0[128], g_part1[128], g_part2[256];

__device__ __forceinline__ float b2f(short s) {
  union { unsigned u; float f; } v; v.u = ((unsigned)(unsigned short)s) << 16; return v.f;
}
__device__ __forceinline__ short f2b(float f) {
  union { float f; unsigned u; } v; v.f = f;
  unsigned u = v.u;
  u += 0x7FFFu + ((u >> 16) & 1u);
  return (short)(u >> 16);
}
// packed f32x2 -> bf16x2 (v_cvt_pk_bf16_f32, RNE — bit-identical to f2b pairs)
__device__ __forceinline__ unsigned pkbf(float a, float b) {
  union { __hip_bfloat162 h; unsigned u; } v;
  v.h = __float22bfloat162_rn(make_float2(a, b));
  return v.u;
}
__device__ __forceinline__ unsigned long long bperm64(unsigned long long v, int byteaddr) {
  int lo = __builtin_amdgcn_ds_bpermute(byteaddr, (int)(unsigned)(v & 0xFFFFFFFFULL));
  int hi = __builtin_amdgcn_ds_bpermute(byteaddr, (int)(unsigned)(v >> 32));
  return (((unsigned long long)(unsigned)hi) << 32) | (unsigned)lo;
}
__device__ __forceinline__ unsigned long long u64min(unsigned long long a, unsigned long long b) {
  return a < b ? a : b;
}
// bitonic compare-exchange step: keep min (mx=0) or max (mx=1) of (v, pv)
__device__ __forceinline__ unsigned long long selstage(unsigned long long v,
                                                       unsigned long long pv, bool mx) {
  bool lt = v < pv;
  return (lt != mx) ? v : pv;
}

// sort 32 buffered candidates (vB, one per lane within a 32-lane half) ascending,
// merge lowest-32 of (vL ∪ vB) back into vL (sorted), refresh worst_hi/wd.
__device__ __forceinline__ void knn_merge32(unsigned long long& vL,
                                            unsigned long long& worst,
                                            unsigned& worst_hi, float& wd,
                                            unsigned long long vB, int hl,
                                            int aX1, int aX2, int aX4, int aX8,
                                            int aX16, int aRev, int aW) {
  vB = selstage(vB, bperm64(vB, aX1),  ((hl & 1) != 0) != ((hl & 2) != 0));
  vB = selstage(vB, bperm64(vB, aX2),  ((hl & 2) != 0) != ((hl & 4) != 0));
  vB = selstage(vB, bperm64(vB, aX1),  ((hl & 1) != 0) != ((hl & 4) != 0));
  vB = selstage(vB, bperm64(vB, aX4),  ((hl & 4) != 0) != ((hl & 8) != 0));
  vB = selstage(vB, bperm64(vB, aX2),  ((hl & 2) != 0) != ((hl & 8) != 0));
  vB = selstage(vB, bperm64(vB, aX1),  ((hl & 1) != 0) != ((hl & 8) != 0));
  vB = selstage(vB, bperm64(vB, aX8),  ((hl & 8) != 0) != ((hl & 16) != 0));
  vB = selstage(vB, bperm64(vB, aX4),  ((hl & 4) != 0) != ((hl & 16) != 0));
  vB = selstage(vB, bperm64(vB, aX2),  ((hl & 2) != 0) != ((hl & 16) != 0));
  vB = selstage(vB, bperm64(vB, aX1),  ((hl & 1) != 0) != ((hl & 16) != 0));
  vB = selstage(vB, bperm64(vB, aX16), (hl & 16) != 0);
  vB = selstage(vB, bperm64(vB, aX8),  (hl & 8) != 0);
  vB = selstage(vB, bperm64(vB, aX4),  (hl & 4) != 0);
  vB = selstage(vB, bperm64(vB, aX2),  (hl & 2) != 0);
  vB = selstage(vB, bperm64(vB, aX1),  (hl & 1) != 0);
  // vL asc, vB asc: pair lane i with reversed buffer -> lowest 32 (bitonic), then cleanup
  vL = u64min(vL, bperm64(vB, aRev));
  vL = selstage(vL, bperm64(vL, aX16), (hl & 16) != 0);
  vL = selstage(vL, bperm64(vL, aX8),  (hl & 8) != 0);
  vL = selstage(vL, bperm64(vL, aX4),  (hl & 4) != 0);
  vL = selstage(vL, bperm64(vL, aX2),  (hl & 2) != 0);
  vL = selstage(vL, bperm64(vL, aX1),  (hl & 1) != 0);
  worst = bperm64(vL, aW);
  worst_hi = (unsigned)(worst >> 32);
  unsigned wh = worst_hi;
  unsigned ub = (wh & 0x80000000u) ? (wh ^ 0x80000000u) : ~wh;
  wd = (wh == 0xFFFFFFFFu) ? __builtin_inff() : __uint_as_float(ub);
}

// ---------------- setup: tpose (blk<512) | copy+pack (512..639) | wprep (640) ----------------
__global__ __launch_bounds__(256) void k_setup(const float* __restrict__ xyz,
                                               const float* __restrict__ points,
                                               const float* __restrict__ W0,
                                               const float* __restrict__ W1,
                                               const float* __restrict__ W2,
                                               float* __restrict__ out) {
#pragma clang fp contract(off)
  __shared__ float tile[64][65];
  int blk = blockIdx.x;
  int t = threadIdx.x;
  if (blk < 512) {
    int b  = blk >> 8;
    int n0 = (blk & 255) << 6;
#pragma unroll
    for (int r = 0; r < 16; r++) {
      int lin = r * 256 + t;
      int c = lin >> 6, nn = lin & 63;
      tile[c][nn] = points[((size_t)(b * 64 + c)) * N_ALL + n0 + nn];
    }
    __syncthreads();
#pragma unroll
    for (int r = 0; r < 16; r++) {
      int lin = r * 256 + t;
      int nn = lin >> 6, c = lin & 63;
      g_ptb[((size_t)(b * N_ALL + n0 + nn)) * 64 + c] = f2b(tile[c][nn]);
    }
  } else if (blk < 640) {
    int i = (blk - 512) * 256 + t;   // < 32768
    if (i < 24576) {
      int s = i & 4095;
      int c = (i >> 12) % 3;
      int b = i / 12288;
      out[i] = xyz[(b * 3 + c) * N_ALL + s];
    }
    int b = i >> 14, n = i & 16383;
    const float* xb = xyz + b * 3 * N_ALL;
    float x = xb[n], y = xb[N_ALL + n], z = xb[2 * N_ALL + n];
    float4 p; p.x = x; p.y = y; p.z = z; p.w = x * x + y * y + z * z;
    ((float4*)g_pxyzn)[i] = p;
  } else {
    for (int i = t; i < 4 * 3 * 64 * 8; i += 256) {
      int j = i & 7, lane = (i >> 3) & 63, rest = i >> 9;
      int kt = rest % 3, mt = rest / 3;
      int m = 16 * mt + (lane & 15);
      int k = 32 * kt + (lane >> 4) * 8 + j;
      float v = 0.f;
      if (k < 64) v = W0[m * 67 + 3 + k];
      else if (k < 67) v = W0[m * 67 + (k - 64)];
      g_Wb0[i] = f2b(v);
    }
    for (int i = t; i < 4 * 2 * 64 * 8; i += 256) {
      int j = i & 7, lane = (i >> 3) & 63;
      int kt = (i >> 9) & 1, mt = i >> 10;
      int m = 16 * mt + (lane & 15);
      int k = 32 * kt + (lane >> 4) * 8 + j;
      g_Wb1[i] = f2b(W1[m * 64 + k]);
    }
    for (int i = t; i < 8 * 2 * 64 * 8; i += 256) {
      int j = i & 7, lane = (i >> 3) & 63;
      int kt = (i >> 9) & 1, mt = i >> 10;
      int m = 16 * mt + (lane & 15);
      int k = 32 * kt + (lane >> 4) * 8 + j;
      g_Wb2[i] = f2b(W2[m * 64 + k]);
    }
    if (t < 128) { g_part0[t] = 0.f; g_part1[t] = 0.f; }
    g_part2[t] = 0.f;
  }
}

// ---------------- KNN: split-N 2-way, 2 queries/wave, float gate + survivor-only keys ----------------
__global__ __launch_bounds__(256, 8) void k_knn() {
#pragma clang fp contract(off)
  __shared__ unsigned long long buf[4][2][64];
  int wv = threadIdx.x >> 6;
  int lane = threadIdx.x & 63;
  int half = lane >> 5;            // 0: lanes 0..31 (query A), 1: lanes 32..63 (query B)
  int hl = lane & 31;
  int lanebase = lane & 32;
  unsigned long long* bufh = buf[wv][half];

  int qpair = wv >> 1;             // waves {0,1} share queries, {2,3} share queries
  int range = wv & 1;              // 0: points [0,8192), 1: [8192,16384)
  int q = blockIdx.x * 4 + qpair * 2 + half;   // 0..8191
  int b = q >> 12, s = q & 4095;
  const float4* pb = (const float4*)g_pxyzn + (b << 14);
  float4 qp = pb[s];
  float qx = qp.x, qy = qp.y, qz = qp.z, qn = qp.w;

  // hoisted cross-lane byte addresses (stay within own 32-lane half)
  int aX1  = (lanebase | (hl ^ 1))  << 2;
  int aX2  = (lanebase | (hl ^ 2))  << 2;
  int aX4  = (lanebase | (hl ^ 4))  << 2;
  int aX8  = (lanebase | (hl ^ 8))  << 2;
  int aX16 = (lanebase | (hl ^ 16)) << 2;
  int aRev = (lanebase | (31 - hl)) << 2;
  int aW   = (lanebase | 31)        << 2;

  unsigned long long vL = ~0ULL;      // per-half sorted top-32 (ascending by lane)
  unsigned long long worst = ~0ULL;   // per-lane copy of own half's vL[31]
  unsigned worst_hi = 0xFFFFFFFFu;
  float wd = __builtin_inff();        // worst distance as float (conservative gate)
  int F = 0;                          // buffered-candidate count (uniform within half)

  int base = range << 13;
  for (int n0 = base; n0 < base + 8192; n0 += 128) {
    float4 p0 = pb[n0 + hl];
    float4 p1 = pb[n0 + 32 + hl];
    float4 p2 = pb[n0 + 64 + hl];
    float4 p3 = pb[n0 + 96 + hl];
    float d[4];
    {
      float dt0 = (qx * p0.x + qy * p0.y) + qz * p0.z;   // contract off: exact ref order
      float dt1 = (qx * p1.x + qy * p1.y) + qz * p1.z;
      float dt2 = (qx * p2.x + qy * p2.y) + qz * p2.z;
      float dt3 = (qx * p3.x + qy * p3.y) + qz * p3.z;
      d[0] = __builtin_fmaf(-2.0f, dt0, qn + p0.w);      // == (qn+pn) - 2*dt exactly
      d[1] = __builtin_fmaf(-2.0f, dt1, qn + p1.w);
      d[2] = __builtin_fmaf(-2.0f, dt2, qn + p2.w);
      d[3] = __builtin_fmaf(-2.0f, dt3, qn + p3.w);
    }
    float md = fminf(fminf(d[0], d[1]), fminf(d[2], d[3]));
    if (__ballot(md <= wd)) {
#pragma unroll
      for (int t = 0; t < 4; t++) {
        bool sv = d[t] <= wd;           // float gate: conservative superset of exact u64 test
        unsigned long long bl = __ballot(sv);
        unsigned mb = half ? (unsigned)(bl >> 32) : (unsigned)bl;
        if (sv) {                       // survivors only: build exact u64 key (masked, no branch)
          unsigned u = __float_as_uint(d[t]);
          u ^= ((unsigned)(((int)u) >> 31)) | 0x80000000u;   // order-preserving map
          unsigned long long c = (((unsigned long long)u) << 32)
                               | (unsigned)(n0 + 32 * t + hl);
          bufh[F + __popc(mb & ((1u << hl) - 1u))] = c;
        }
        F += __popc(mb);
        if (__ballot(F >= 32)) {          // coherent: both halves merge together
          int take = F >= 32 ? 32 : F;    // partner half consumes its partial buffer
          unsigned long long vB = (hl < take) ? bufh[hl] : ~0ULL;
          knn_merge32(vL, worst, worst_hi, wd, vB, hl,
                      aX1, aX2, aX4, aX8, aX16, aRev, aW);
          int R = F - take;               // 0..31
          if (hl < R) bufh[hl] = bufh[32 + hl];   // reads 32..62, writes 0..30: disjoint
          F = R;
        }
      }
    }
  }
  if (__ballot(F > 0)) {   // flush remaining (<32) with +inf padding
    unsigned long long vB = (hl < F) ? bufh[hl] : ~0ULL;
    knn_merge32(vL, worst, worst_hi, wd, vB, hl, aX1, aX2, aX4, aX8, aX16, aRev, aW);
  }

  // cross-wave combine: waves (2k, 2k+1) hold lo/hi top-32 for the same queries
  bufh[hl] = vL;
  __syncthreads();
  unsigned long long vB = buf[wv ^ 1][half][hl];
  vL = u64min(vL, bperm64(vB, aRev));            // both sorted asc: reverse-pair min
  vL = selstage(vL, bperm64(vL, aX16), (hl & 16) != 0);
  vL = selstage(vL, bperm64(vL, aX8),  (hl & 8) != 0);
  vL = selstage(vL, bperm64(vL, aX4),  (hl & 4) != 0);
  vL = selstage(vL, bperm64(vL, aX2),  (hl & 2) != 0);
  vL = selstage(vL, bperm64(vL, aX1),  (hl & 1) != 0);
  if (range == 0)
    g_knn[((size_t)q << 5) | hl] = (unsigned short)(vL & 0xFFFF);
}

// ---------------- layer0: gather feats to LDS, MFMA K=96 -> x0 bf16 ----------------
__global__ __launch_bounds__(256) void k_l0(const float* __restrict__ xyz) {
  __shared__ short feats[256][104];   // row 208B: 16B-aligned
  int t = threadIdx.x;
  int p0 = blockIdx.x * 256;
  {
    int p = p0 + t;
    int idx = g_knn[p];
    int s = (p >> 5) & 4095;
    int b = p >> 17;
    const short* src = g_ptb + ((size_t)((b << 14) + idx) << 6);
#pragma unroll
    for (int i = 0; i < 8; i++)
      ((int4*)&feats[t][0])[i] = ((const int4*)src)[i];
    const float* xb = xyz + b * 3 * N_ALL;
    int4 z; z.x = 0; z.y = 0; z.z = 0; z.w = 0;      // vectorized zero-fill [64..95]
    *(int4*)&feats[t][64] = z;
    *(int4*)&feats[t][72] = z;
    *(int4*)&feats[t][80] = z;
    *(int4*)&feats[t][88] = z;
    short4 d3;
    d3.x = f2b(xb[idx] - xb[s]);
    d3.y = f2b(xb[N_ALL + idx] - xb[N_ALL + s]);
    d3.z = f2b(xb[2 * N_ALL + idx] - xb[2 * N_ALL + s]);
    d3.w = 0;
    *(short4*)&feats[t][64] = d3;                     // overwrites [64..67]
  }
  __syncthreads();
  int lane = t & 63, wv = t >> 6;
  int l15 = lane & 15, quad = lane >> 4;
  bf16x8 A[4][3];
#pragma unroll
  for (int mt = 0; mt < 4; mt++)
#pragma unroll
    for (int kt = 0; kt < 3; kt++)
      A[mt][kt] = *(const bf16x8*)(g_Wb0 + (((mt * 3 + kt) * 64 + lane) << 3));
  f32x4 C[4][4];
#pragma unroll
  for (int mt = 0; mt < 4; mt++)
#pragma unroll
    for (int nt = 0; nt < 4; nt++) C[mt][nt] = 0.f;
#pragma unroll
  for (int kt = 0; kt < 3; kt++)
#pragma unroll
    for (int nt = 0; nt < 4; nt++) {
      bf16x8 B = *(const bf16x8*)(&feats[wv * 64 + nt * 16 + l15][kt * 32 + quad * 8]);
#pragma unroll
      for (int mt = 0; mt < 4; mt++)
        C[mt][nt] = __builtin_amdgcn_mfma_f32_16x16x32_bf16(A[mt][kt], B, C[mt][nt], 0, 0, 0);
    }
#pragma unroll
  for (int mt = 0; mt < 4; mt++)
#pragma unroll
    for (int nt = 0; nt < 4; nt++) {
      int p = p0 + wv * 64 + nt * 16 + l15;
      int c0 = mt * 16 + quad * 4;
      uint2 o;
      o.x = pkbf(C[mt][nt][0], C[mt][nt][1]);
      o.y = pkbf(C[mt][nt][2], C[mt][nt][3]);
      *(uint2*)(g_x0b + ((size_t)p << 6) + c0) = o;
    }
}

// ---------------- layer1: BN0+leaky on x0 frags, MFMA K=64 -> x1 bf16 ----------------
__global__ __launch_bounds__(256) void k_l1(const float* __restrict__ g0,
                                            const float* __restrict__ b0) {
  __shared__ float scA[64], shA[64];
  int t = threadIdx.x;
  if (t < 64) {
    float m = g_part0[t] / P_TOTF;
    float v = g_part0[64 + t] / P_TOTF - m * m;
    float sc = g0[t] / sqrtf(v + EPSV);
    scA[t] = sc; shA[t] = b0[t] - m * sc;
  }
  __syncthreads();
  int lane = t & 63, wv = t >> 6;
  int l15 = lane & 15, quad = lane >> 4;
  int p0 = blockIdx.x * 256 + wv * 64;
  float scv[2][8], shv[2][8];
#pragma unroll
  for (int kt = 0; kt < 2; kt++)
#pragma unroll
    for (int j = 0; j < 8; j++) {
      int c = kt * 32 + quad * 8 + j;
      scv[kt][j] = scA[c]; shv[kt][j] = shA[c];
    }
  bf16x8 A[4][2];
#pragma unroll
  for (int mt = 0; mt < 4; mt++)
#pragma unroll
    for (int kt = 0; kt < 2; kt++)
      A[mt][kt] = *(const bf16x8*)(g_Wb1 + (((mt * 2 + kt) * 64 + lane) << 3));
  f32x4 C[4][4];
#pragma unroll
  for (int mt = 0; mt < 4; mt++)
#pragma unroll
    for (int nt = 0; nt < 4; nt++) C[mt][nt] = 0.f;
#pragma unroll
  for (int kt = 0; kt < 2; kt++)
#pragma unroll
    for (int nt = 0; nt < 4; nt++) {
      const short* src = g_x0b + (((size_t)(p0 + nt * 16 + l15)) << 6) + kt * 32 + quad * 8;
      uint4 raw = *(const uint4*)src;
      bf16x8 B;
      unsigned* Bu = (unsigned*)&B;
      unsigned ru[4] = {raw.x, raw.y, raw.z, raw.w};
#pragma unroll
      for (int jj = 0; jj < 4; jj++) {
        float lo = __uint_as_float(ru[jj] << 16);
        float hi = __uint_as_float(ru[jj] & 0xFFFF0000u);
        float a0 = lo * scv[kt][2*jj]   + shv[kt][2*jj];
        float a1 = hi * scv[kt][2*jj+1] + shv[kt][2*jj+1];
        a0 = fmaxf(a0, 0.1f * a0);
        a1 = fmaxf(a1, 0.1f * a1);
        Bu[jj] = pkbf(a0, a1);
      }
#pragma unroll
      for (int mt = 0; mt < 4; mt++)
        C[mt][nt] = __builtin_amdgcn_mfma_f32_16x16x32_bf16(A[mt][kt], B, C[mt][nt], 0, 0, 0);
    }
#pragma unroll
  for (int mt = 0; mt < 4; mt++)
#pragma unroll
    for (int nt = 0; nt < 4; nt++) {
      int p = p0 + nt * 16 + l15;
      int c0 = mt * 16 + quad * 4;
      uint2 o;
      o.x = pkbf(C[mt][nt][0], C[mt][nt][1]);
      o.y = pkbf(C[mt][nt][2], C[mt][nt][3]);
      *(uint2*)(g_x1b + ((size_t)p << 6) + c0) = o;
    }
}

// ---------------- layer2: BN1+leaky on x1 frags, MFMA K=64 M=128 -> x2 bf16 ----------------
__global__ __launch_bounds__(256) void k_l2(const float* __restrict__ g1,
                                            const float* __restrict__ b1) {
  __shared__ float scA[64], shA[64];
  int t = threadIdx.x;
  if (t < 64) {
    float m = g_part1[t] / P_TOTF;
    float v = g_part1[64 + t] / P_TOTF - m * m;
    float sc = g1[t] / sqrtf(v + EPSV);
    scA[t] = sc; shA[t] = b1[t] - m * sc;
  }
  __syncthreads();
  int lane = t & 63, wv = t >> 6;
  int l15 = lane & 15, quad = lane >> 4;
  int chh = wv & 1;                      // channel half
  int p0 = blockIdx.x * 128 + (wv >> 1) * 64;
  float scv[2][8], shv[2][8];
#pragma unroll
  for (int kt = 0; kt < 2; kt++)
#pragma unroll
    for (int j = 0; j < 8; j++) {
      int c = kt * 32 + quad * 8 + j;
      scv[kt][j] = scA[c]; shv[kt][j] = shA[c];
    }
  bf16x8 A[4][2];
#pragma unroll
  for (int mt = 0; mt < 4; mt++)
#pragma unroll
    for (int kt = 0; kt < 2; kt++)
      A[mt][kt] = *(const bf16x8*)(g_Wb2 + ((((4 * chh + mt) * 2 + kt) * 64 + lane) << 3));
  f32x4 C[4][4];
#pragma unroll
  for (int mt = 0; mt < 4; mt++)
#pragma unroll
    for (int nt = 0; nt < 4; nt++) C[mt][nt] = 0.f;
#pragma unroll
  for (int kt = 0; kt < 2; kt++)
#pragma unroll
    for (int nt = 0; nt < 4; nt++) {
      const short* src = g_x1b + (((size_t)(p0 + nt * 16 + l15)) << 6) + kt * 32 + quad * 8;
      uint4 raw = *(const uint4*)src;
      bf16x8 B;
      unsigned* Bu = (unsigned*)&B;
      unsigned ru[4] = {raw.x, raw.y, raw.z, raw.w};
#pragma unroll
      for (int jj = 0; jj < 4; jj++) {
        float lo = __uint_as_float(ru[jj] << 16);
        float hi = __uint_as_float(ru[jj] & 0xFFFF0000u);
        float a0 = lo * scv[kt][2*jj]   + shv[kt][2*jj];
        float a1 = hi * scv[kt][2*jj+1] + shv[kt][2*jj+1];
        a0 = fmaxf(a0, 0.1f * a0);
        a1 = fmaxf(a1, 0.1f * a1);
        Bu[jj] = pkbf(a0, a1);
      }
#pragma unroll
      for (int mt = 0; mt < 4; mt++)
        C[mt][nt] = __builtin_amdgcn_mfma_f32_16x16x32_bf16(A[mt][kt], B, C[mt][nt], 0, 0, 0);
    }
#pragma unroll
  for (int mt = 0; mt < 4; mt++)
#pragma unroll
    for (int nt = 0; nt < 4; nt++) {
      int p = p0 + nt * 16 + l15;
      int c0 = (4 * chh + mt) * 16 + quad * 4;
      uint2 o;
      o.x = pkbf(C[mt][nt][0], C[mt][nt][1]);
      o.y = pkbf(C[mt][nt][2], C[mt][nt][3]);
      *(uint2*)(g_x2b + ((size_t)p << 7) + c0) = o;
    }
}

// ---------------- streaming stats over bf16 [p][64] ----------------
__global__ __launch_bounds__(256) void k_red64(const short* __restrict__ x,
                                               float* __restrict__ part) {
  int t = threadIdx.x;
  int cl = t & 31, pr = t >> 5;
  float s0 = 0.f, s1 = 0.f, q0 = 0.f, q1 = 0.f;
  int pbase = blockIdx.x * 1024;
  for (int i = 0; i < 128; i++) {
    int p = pbase + pr + i * 8;
    unsigned d = *(const unsigned*)(x + ((size_t)p << 6) + cl * 2);
    float a = b2f((short)(d & 0xFFFF));
    float b = b2f((short)(d >> 16));
    s0 += a; q0 = fmaf(a, a, q0);
    s1 += b; q1 = fmaf(b, b, q1);
  }
  __shared__ float sm[8][64], sq[8][64];
  sm[pr][cl * 2] = s0; sm[pr][cl * 2 + 1] = s1;
  sq[pr][cl * 2] = q0; sq[pr][cl * 2 + 1] = q1;
  __syncthreads();
  if (t < 64) {
    float S = 0.f, Q = 0.f;
#pragma unroll
    for (int r = 0; r < 8; r++) { S += sm[r][t]; Q += sq[r][t]; }
    atomicAdd(part + t, S); atomicAdd(part + 64 + t, Q);
  }
}

// ---------------- stats + per-(s,c) max/min over bf16 [p][128] ----------------
// thread owns (group, channel-pair): max/min need no cross-lane reduce; S,Q reduced as before.
__global__ __launch_bounds__(256) void k_red128mx(const short* __restrict__ x,
                                                  float* __restrict__ part) {
  int t = threadIdx.x;
  int cl = t & 63, wv = t >> 6;
  float s0 = 0.f, s1 = 0.f, q0 = 0.f, q1 = 0.f;
  int g0 = blockIdx.x * 32;            // 32 k-groups (1024 points) per block
  for (int it = 0; it < 8; it++) {
    int g = g0 + it * 4 + wv;
    size_t pbase = (size_t)g << 5;
    float mx0 = -3.4e38f, mn0 = 3.4e38f, mx1 = -3.4e38f, mn1 = 3.4e38f;
#pragma unroll
    for (int k = 0; k < 32; k++) {
      unsigned d = *(const unsigned*)(x + ((pbase + k) << 7) + cl * 2);
      float a = __uint_as_float(d << 16);
      float b = __uint_as_float(d & 0xFFFF0000u);
      s0 += a; q0 = fmaf(a, a, q0);
      s1 += b; q1 = fmaf(b, b, q1);
      mx0 = fmaxf(mx0, a); mn0 = fminf(mn0, a);
      mx1 = fmaxf(mx1, b); mn1 = fminf(mn1, b);
    }
    float2 vmx; vmx.x = mx0; vmx.y = mx1;
    float2 vmn; vmn.x = mn0; vmn.y = mn1;
    *(float2*)(g_mx + ((size_t)g << 7) + cl * 2) = vmx;
    *(float2*)(g_mn + ((size_t)g << 7) + cl * 2) = vmn;
  }
  __shared__ float sm[4][128], sq[4][128];
  sm[wv][cl * 2] = s0; sm[wv][cl * 2 + 1] = s1;
  sq[wv][cl * 2] = q0; sq[wv][cl * 2 + 1] = q1;
  __syncthreads();
  if (t < 128) {
    float S = 0.f, Q = 0.f;
#pragma unroll
    for (int r = 0; r < 4; r++) { S += sm[r][t]; Q += sq[r][t]; }
    atomicAdd(part + t, S); atomicAdd(part + 128 + t, Q);
  }
}

// ---------------- epilogue: BN2+leaky on precomputed max/min, coalesced r/w ----------------
__global__ __launch_bounds__(256) void k_epi(const float* __restrict__ g2,
                                             const float* __restrict__ b2,
                                             float* __restrict__ out) {
  __shared__ float scA[128], shA[128];
  __shared__ float res[16][132];
  int t = threadIdx.x;
  if (t < 128) {
    float m = g_part2[t] / P_TOTF;
    float v = g_part2[128 + t] / P_TOTF - m * m;
    float sc = g2[t] / sqrtf(v + EPSV);
    scA[t] = sc; shA[t] = b2[t] - m * sc;
  }
  __syncthreads();
  int cp = t & 63, sl = t >> 6;        // channels 2cp,2cp+1 ; sl in 0..3
  int c0 = cp * 2, c1 = c0 + 1;
  float sc0 = scA[c0], sh0 = shA[c0];
  float sc1 = scA[c1], sh1 = shA[c1];
  int sg0 = blockIdx.x * 16;
  for (int it = 0; it < 4; it++) {
    int sgl = sl * 4 + it;             // 0..15, each once per block
    size_t off = ((size_t)(sg0 + sgl) << 7) + c0;
    float2 vmx = *(const float2*)(g_mx + off);
    float2 vmn = *(const float2*)(g_mn + off);
    float a0 = (sc0 >= 0.f ? vmx.x : vmn.x) * sc0 + sh0; a0 = fmaxf(a0, 0.1f * a0);
    float a1 = (sc1 >= 0.f ? vmx.y : vmn.y) * sc1 + sh1; a1 = fmaxf(a1, 0.1f * a1);
    res[sgl][c0] = a0; res[sgl][c1] = a1;
  }
  __syncthreads();
  int b = sg0 >> 12, s0 = sg0 & 4095;   // block never straddles b (4096 % 16 == 0)
#pragma unroll
  for (int w = 0; w < 2; w++) {
    int fidx = t * 2 + w;               // 0..511
    int c = fidx >> 2, qi = fidx & 3;
    float4 o;
    o.x = res[qi * 4 + 0][c];
    o.y = res[qi * 4 + 1][c];
    o.z = res[qi * 4 + 2][c];
    o.w = res[qi * 4 + 3][c];
    *(float4*)(out + 24576 + (((size_t)(b * 128 + c)) << 12) + s0 + qi * 4) = o;
  }
}

extern "C" void kernel_launch(void* const* d_in, const int* in_sizes, int n_in,
                              void* d_out, int out_size, void* d_ws, size_t ws_size,
                              hipStream_t stream) {
  (void)in_sizes; (void)n_in; (void)out_size; (void)d_ws; (void)ws_size;
  const float* xyz    = (const float*)d_in[0];
  const float* points = (const float*)d_in[1];
  const float* W0     = (const float*)d_in[2];
  const float* W1     = (const float*)d_in[3];
  const float* W2     = (const float*)d_in[4];
  const float* g0     = (const float*)d_in[5];
  const float* b0     = (const float*)d_in[6];
  const float* g1     = (const float*)d_in[7];
  const float* b1     = (const float*)d_in[8];
  const float* g2     = (const float*)d_in[9];
  const float* b2     = (const float*)d_in[10];
  float* out = (float*)d_out;

  short *x0b, *x1b, *x2b; float *part0, *part1, *part2;
  hipGetSymbolAddress((void**)&x0b,   HIP_SYMBOL(g_x0b));
  hipGetSymbolAddress((void**)&x1b,   HIP_SYMBOL(g_x1b));
  hipGetSymbolAddress((void**)&x2b,   HIP_SYMBOL(g_x2b));
  hipGetSymbolAddress((void**)&part0, HIP_SYMBOL(g_part0));
  hipGetSymbolAddress((void**)&part1, HIP_SYMBOL(g_part1));
  hipGetSymbolAddress((void**)&part2, HIP_SYMBOL(g_part2));

  hipLaunchKernelGGL(k_setup,    dim3(641),  dim3(256), 0, stream, xyz, points, W0, W1, W2, out);
  hipLaunchKernelGGL(k_knn,      dim3(2048), dim3(256), 0, stream);
  hipLaunchKernelGGL(k_l0,       dim3(1024), dim3(256), 0, stream, xyz);
  hipLaunchKernelGGL(k_red64,    dim3(256),  dim3(256), 0, stream, x0b, part0);
  hipLaunchKernelGGL(k_l1,       dim3(1024), dim3(256), 0, stream, g0, b0);
  hipLaunchKernelGGL(k_red64,    dim3(256),  dim3(256), 0, stream, x1b, part1);
  hipLaunchKernelGGL(k_l2,       dim3(2048), dim3(256), 0, stream, g1, b1);
  hipLaunchKernelGGL(k_red128mx, dim3(256),  dim3(256), 0, stream, x2b, part2);
  hipLaunchKernelGGL(k_epi,      dim3(512),  dim3(256), 0, stream, g2, b2, out);
}